// Round 2
// baseline (225.364 us; speedup 1.0000x reference)
//
#include <hip/hip_runtime.h>

// Problem constants
constexpr int Bz  = 8;
constexpr int Lz  = 512;
constexpr int Hz  = 256;
constexpr int H2z = 512;
constexpr int Vz  = 32000;
constexpr int Mz  = Bz * Lz;      // 4096 tokens
constexpr float CF = 0.05f;       // 1 - ALPHA
constexpr int NB  = 16;           // 16 blocks of 32 = 512 (511 real + 1 dummy)

typedef __attribute__((ext_vector_type(8))) short bfrag8;   // 8 bf16
typedef __attribute__((ext_vector_type(4))) float f32x4v;
typedef __attribute__((ext_vector_type(4))) short s4v;

static __device__ __forceinline__ short f2bf(float f) {
  unsigned u = __builtin_bit_cast(unsigned, f);
  u += 0x7fffu + ((u >> 16) & 1u);           // round-to-nearest-even
  return (short)(u >> 16);
}

// ---------------------------------------------------------------------------
// Weight transpose+convert, both W1 and W2 in one launch. dst[n][k]=bf16(src[k][n])
// ---------------------------------------------------------------------------
static __device__ __forceinline__ void wcvt_tile(
    const float* __restrict__ src, short* __restrict__ dst,
    int K, int N, int n0, int k0, int tid)
{
  __shared__ float tile[64][68];
  const int rr = tid >> 4, c4 = (tid & 15) << 2;
#pragma unroll
  for (int q = 0; q < 4; ++q) {
    const int kr = rr + q * 16;
    *(float4*)&tile[kr][c4] = *(const float4*)(src + (long)(k0 + kr) * N + n0 + c4);
  }
  __syncthreads();
#pragma unroll
  for (int q = 0; q < 4; ++q) {
    const int nr = rr + q * 16;
    s4v o = { f2bf(tile[c4 + 0][nr]), f2bf(tile[c4 + 1][nr]),
              f2bf(tile[c4 + 2][nr]), f2bf(tile[c4 + 3][nr]) };
    *(s4v*)(dst + (long)(n0 + nr) * K + k0 + c4) = o;
  }
}

__global__ __launch_bounds__(256) void k_wcvt2(
    const float* __restrict__ W1, const float* __restrict__ W2,
    short* __restrict__ Wt1, short* __restrict__ Wt2)
{
  const int bx = blockIdx.x, tid = threadIdx.x;
  if (bx < 32) {
    wcvt_tile(W1, Wt1, Hz, H2z, (bx & 7) * 64, (bx >> 3) * 64, tid);
  } else {
    const int b2 = bx - 32;
    wcvt_tile(W2, Wt2, H2z, Hz, (b2 & 3) * 64, (b2 >> 2) * 64, tid);
  }
}

// ---------------------------------------------------------------------------
// MFMA GEMM1 with fused embedding gather:
// y1bf[4096,512] = bf16(relu(bf16(embed[seq]) @ Wt1^T + b1))
// ---------------------------------------------------------------------------
__global__ __launch_bounds__(256) void k_mfma1(
    const int* __restrict__ seq, const float* __restrict__ embed,
    const short* __restrict__ Wt1, const float* __restrict__ b1,
    short* __restrict__ y1bf)
{
  __shared__ short As[64][32];
  __shared__ short Bs[64][32];
  const int tid = threadIdx.x;
  const int n0 = blockIdx.x * 64, m0 = blockIdx.y * 64;
  const int w = tid >> 6, l = tid & 63;
  const int srow = tid >> 2, skq = (tid & 3) << 3;
  const long abase = (long)seq[m0 + srow] * Hz;
  const f32x4v zero = {0.f, 0.f, 0.f, 0.f};
  f32x4v acc[4] = {zero, zero, zero, zero};
  for (int kc = 0; kc < Hz; kc += 32) {
    const float4 a0 = *(const float4*)(embed + abase + kc + skq);
    const float4 a1 = *(const float4*)(embed + abase + kc + skq + 4);
    const bfrag8 bvl = *(const bfrag8*)(Wt1 + (long)(n0 + srow) * Hz + kc + skq);
    __syncthreads();
    bfrag8 av = { f2bf(a0.x), f2bf(a0.y), f2bf(a0.z), f2bf(a0.w),
                  f2bf(a1.x), f2bf(a1.y), f2bf(a1.z), f2bf(a1.w) };
    *(bfrag8*)&As[srow][skq] = av;
    *(bfrag8*)&Bs[srow][skq] = bvl;
    __syncthreads();
    const bfrag8 a = *(const bfrag8*)&As[(w << 4) + (l & 15)][(l >> 4) << 3];
#pragma unroll
    for (int nn = 0; nn < 4; ++nn) {
      const bfrag8 bb = *(const bfrag8*)&Bs[(nn << 4) + (l & 15)][(l >> 4) << 3];
      acc[nn] = __builtin_amdgcn_mfma_f32_16x16x32_bf16(a, bb, acc[nn], 0, 0, 0);
    }
  }
  const int col0 = l & 15, quad = l >> 4;
#pragma unroll
  for (int nn = 0; nn < 4; ++nn) {
    const int col = n0 + (nn << 4) + col0;
    const float bias = b1[col];
#pragma unroll
    for (int i = 0; i < 4; ++i) {
      const int row = m0 + (w << 4) + (quad << 2) + i;
      y1bf[(long)row * H2z + col] = f2bf(fmaxf(acc[nn][i] + bias, 0.0f));
    }
  }
}

// ---------------------------------------------------------------------------
// FUSED GEMM2 + residual + LayerNorm + L2-normalize, full-occupancy version.
// Grid: 256 blocks x 16 rows. 4 waves split the 256 cols (64 each, 4 frags).
// LN row stats reduced in-quad then combined across the 4 waves via LDS.
// Writes h (fp32 t-order), hn (fp32 t-order), Knb (bf16 s-order, row 511 zero).
// ---------------------------------------------------------------------------
__global__ __launch_bounds__(256) void k_mfma2ln(
    const int* __restrict__ seq, const float* __restrict__ embed,
    const short* __restrict__ y1bf, const short* __restrict__ Wt2,
    const float* __restrict__ b2, const float* __restrict__ gamma,
    const float* __restrict__ beta, float* __restrict__ h,
    float* __restrict__ hn, short* __restrict__ Knb)
{
  __shared__ short As[16][32];     // 1 KB
  __shared__ short Bs[256][32];    // 16 KB (all 256 output cols of Wt2)
  __shared__ float red[4][16][2];  // per-wave LN partials (s, ss)
  __shared__ float red2[4][16];    // per-wave L2 partials
  const int tid = threadIdx.x;
  const int m0 = blockIdx.x * 16;
  const int w = tid >> 6, l = tid & 63;
  const int srow = tid >> 2, skq = (tid & 3) << 3;
  const f32x4v zero = {0.f, 0.f, 0.f, 0.f};
  f32x4v acc[4] = {zero, zero, zero, zero};

  for (int kc = 0; kc < H2z; kc += 32) {
    // issue global loads before the barrier (hide latency under prior MFMA)
    bfrag8 av = {};
    if (tid < 64)
      av = *(const bfrag8*)(y1bf + (long)(m0 + (tid >> 2)) * H2z + kc + skq);
    bfrag8 bv[4];
#pragma unroll
    for (int q = 0; q < 4; ++q)
      bv[q] = *(const bfrag8*)(Wt2 + (long)(srow + (q << 6)) * H2z + kc + skq);
    __syncthreads();
    if (tid < 64) *(bfrag8*)&As[tid >> 2][skq] = av;
#pragma unroll
    for (int q = 0; q < 4; ++q)
      *(bfrag8*)&Bs[srow + (q << 6)][skq] = bv[q];
    __syncthreads();
    const bfrag8 a = *(const bfrag8*)&As[l & 15][(l >> 4) << 3];
#pragma unroll
    for (int nn = 0; nn < 4; ++nn) {
      const bfrag8 bb = *(const bfrag8*)&Bs[(w << 6) + (nn << 4) + (l & 15)][(l >> 4) << 3];
      acc[nn] = __builtin_amdgcn_mfma_f32_16x16x32_bf16(a, bb, acc[nn], 0, 0, 0);
    }
  }

  const int col0 = l & 15, quad = l >> 4;
  float g_r[4], be_r[4], b2_r[4];
#pragma unroll
  for (int nn = 0; nn < 4; ++nn) {
    const int col = (w << 6) + (nn << 4) + col0;
    g_r[nn] = gamma[col]; be_r[nn] = beta[col]; b2_r[nn] = b2[col];
  }

  // pass 1: residual add, per-row mean/var partials (this wave's 64 cols)
  float v[4][4];                    // [i][nn]
#pragma unroll
  for (int i = 0; i < 4; ++i) {
    const int lr = (quad << 2) + i;
    const int row = m0 + lr;
    const long ebase = (long)seq[row] * Hz;
    float s = 0.0f, ss = 0.0f;
#pragma unroll
    for (int nn = 0; nn < 4; ++nn) {
      const int col = (w << 6) + (nn << 4) + col0;
      const float t = acc[nn][i] + b2_r[nn] + embed[ebase + col];
      v[i][nn] = t; s += t; ss += t * t;
    }
#pragma unroll
    for (int o = 8; o >= 1; o >>= 1) { s += __shfl_xor(s, o); ss += __shfl_xor(ss, o); }
    if ((l & 15) == 0) { red[w][lr][0] = s; red[w][lr][1] = ss; }
  }
  __syncthreads();

  // pass 2: LN normalize, per-row L2 partials
#pragma unroll
  for (int i = 0; i < 4; ++i) {
    const int lr = (quad << 2) + i;
    const float s  = red[0][lr][0] + red[1][lr][0] + red[2][lr][0] + red[3][lr][0];
    const float ss = red[0][lr][1] + red[1][lr][1] + red[2][lr][1] + red[3][lr][1];
    const float mu   = s * (1.0f / Hz);
    const float var  = ss * (1.0f / Hz) - mu * mu;
    const float rstd = rsqrtf(var + 1e-5f);
    float hs = 0.0f;
#pragma unroll
    for (int nn = 0; nn < 4; ++nn) {
      const float hv = (v[i][nn] - mu) * rstd * g_r[nn] + be_r[nn];
      v[i][nn] = hv; hs += hv * hv;
    }
#pragma unroll
    for (int o = 8; o >= 1; o >>= 1) hs += __shfl_xor(hs, o);
    if ((l & 15) == 0) red2[w][lr] = hs;
  }
  __syncthreads();

  // pass 3: L2 normalize + stores
#pragma unroll
  for (int i = 0; i < 4; ++i) {
    const int lr = (quad << 2) + i;
    const float hs = red2[0][lr] + red2[1][lr] + red2[2][lr] + red2[3][lr];
    const float inv = 1.0f / fmaxf(sqrtf(hs), 1e-12f);
    const int row = m0 + lr;
    float* hrow  = h  + (long)row * Hz;
    float* hnrow = hn + (long)row * Hz;
    const int bb_ = row >> 9, t = row & 511;
    short* kr = Knb + ((long)bb_ * 512 + (t < 511 ? 510 - t : 511)) * Hz;
#pragma unroll
    for (int nn = 0; nn < 4; ++nn) {
      const int col = (w << 6) + (nn << 4) + col0;
      const float hv = v[i][nn];
      const float nv = hv * inv;
      hrow[col]  = hv;
      hnrow[col] = nv;
      kr[col] = (t < 511) ? f2bf(nv) : (short)0;
    }
  }
}

// ---------------------------------------------------------------------------
// Full Gram via bf16 MFMA (lower tiles), with FUSED block-diag inverse
// (one wave per 32x32 diag block) AND fused p computation: 16 of the idle
// upper-triangle blocks per batch each compute 32 entries of
// p[b][s] = hn[b][510-s] . h[b][511], concurrently with the Gram tiles.
// ---------------------------------------------------------------------------
__global__ __launch_bounds__(256) void k_gramT(
    const short* __restrict__ Knb, const float* __restrict__ h,
    const float* __restrict__ hn, float* __restrict__ G,
    float* __restrict__ Wsol, float* __restrict__ p)
{
  const int nb = blockIdx.x, mb = blockIdx.y, b = blockIdx.z;
  __shared__ short As[64][32];
  __shared__ short Bs[64][32];
  __shared__ float Gs2[2][32][33];
  __shared__ float qs[Hz];
  if (nb > mb) {
    // repurposed idle block: p chunk (block-uniform branch, syncthreads legal)
    const int idx = ((nb * (nb - 1)) >> 1) + mb;   // 0..27 upper-tri enumeration
    if (idx >= 16) return;
    const int tid = threadIdx.x;
    qs[tid] = h[((long)b * Lz + 511) * Hz + tid];
    __syncthreads();
    const int s = idx * 32 + (tid >> 3);           // 32 s-rows per block
    const int g = tid & 7;                         // 8 threads per row, 32 ch each
    float acc = 0.0f;
    if (s <= 510) {
      const float* src = hn + ((long)b * Lz + (510 - s)) * Hz + (g << 5);
#pragma unroll
      for (int q = 0; q < 8; ++q) {
        const float4 vv = *(const float4*)(src + 4 * q);
        const int c = (g << 5) + 4 * q;
        acc += vv.x * qs[c] + vv.y * qs[c + 1] + vv.z * qs[c + 2] + vv.w * qs[c + 3];
      }
    }
#pragma unroll
    for (int o = 4; o >= 1; o >>= 1) acc += __shfl_xor(acc, o);
    if (g == 0) p[(long)b * 512 + s] = acc;        // s==511 writes 0 (dummy)
    return;
  }
  const short* Kb = Knb + (long)b * 512 * Hz;
  const int tid = threadIdx.x;
  const int w = tid >> 6, l = tid & 63;
  const int srow = tid >> 2, skq = (tid & 3) << 3;
  const f32x4v zero = {0.f, 0.f, 0.f, 0.f};
  f32x4v acc[4] = {zero, zero, zero, zero};
  for (int kc = 0; kc < Hz; kc += 32) {
    __syncthreads();
    *(bfrag8*)&As[srow][skq] = *(const bfrag8*)(Kb + (long)(mb * 64 + srow) * Hz + kc + skq);
    *(bfrag8*)&Bs[srow][skq] = *(const bfrag8*)(Kb + (long)(nb * 64 + srow) * Hz + kc + skq);
    __syncthreads();
    const bfrag8 a = *(const bfrag8*)&As[(w << 4) + (l & 15)][(l >> 4) << 3];
#pragma unroll
    for (int nn = 0; nn < 4; ++nn) {
      const bfrag8 bb = *(const bfrag8*)&Bs[(nn << 4) + (l & 15)][(l >> 4) << 3];
      acc[nn] = __builtin_amdgcn_mfma_f32_16x16x32_bf16(a, bb, acc[nn], 0, 0, 0);
    }
  }
  const int col0 = l & 15, quad = l >> 4;
  float* Gb = G + (long)b * 512 * 512;
#pragma unroll
  for (int nn = 0; nn < 4; ++nn) {
    const int col = nb * 64 + (nn << 4) + col0;
#pragma unroll
    for (int i = 0; i < 4; ++i) {
      const int row = mb * 64 + (w << 4) + (quad << 2) + i;
      Gb[(long)row * 512 + col] = acc[nn][i];
    }
  }
  if (mb != nb) return;
#pragma unroll
  for (int nn = 0; nn < 4; ++nn) {
    const int lc = (nn << 4) + col0;
#pragma unroll
    for (int i = 0; i < 4; ++i) {
      const int lr = (w << 4) + (quad << 2) + i;
      if ((lr >> 5) == (lc >> 5)) Gs2[lr >> 5][lr & 31][lc & 31] = acc[nn][i];
    }
  }
  __syncthreads();
  if (w < 2 && l < 32) {       // wave w inverts sub-block w; lane = column c
    const int c = l;
    float wv[32];
    wv[0] = (c == 0) ? 1.0f : 0.0f;
#pragma unroll
    for (int i = 1; i < 32; ++i) {
      float sum = 0.0f;
#pragma unroll
      for (int j = 0; j < i; ++j) sum = fmaf(Gs2[w][i][j], wv[j], sum);
      wv[i] = ((i == c) ? 1.0f : 0.0f) - CF * sum;
    }
    const int blk = mb * 2 + w;
    float* dst = Wsol + ((long)(b * NB + blk) << 10) + c;
#pragma unroll
    for (int i = 0; i < 32; ++i) dst[i * 32] = wv[i];
  }
}

// ---------------------------------------------------------------------------
// Block-triangular solve — only the truly-serial chain. 8 WGs x 256 thr.
// 2 barriers per block-step: off-diag matvec (all threads) -> barrier ->
// wave0 lanes 0-31 do rhs + 32x32 Minv matvec wave-synchronously -> barrier.
// ---------------------------------------------------------------------------
__global__ __launch_bounds__(256) void k_solve(
    const float* __restrict__ G, const float* __restrict__ p,
    const float* __restrict__ Wsol, float* __restrict__ d_all)
{
  __shared__ float ds[512];
  __shared__ float part[32][9];
  __shared__ float rhs[32];
  const int b = blockIdx.x, tid = threadIdx.x;
  const int i = tid >> 3, g = tid & 7;
  const float* Gb = G + (long)b * 512 * 512;
  const float* pb = p + (long)b * 512;

  for (int blk = 0; blk < NB; ++blk) {
    float acc0 = 0.0f, acc1 = 0.0f;
    const float* grow = Gb + (long)(blk * 32 + i) * 512 + (g << 2);
    int bp = 0;
    for (; bp + 1 < blk; bp += 2) {
      const float4 g0 = *(const float4*)(grow + bp * 32);
      const float4 g1 = *(const float4*)(grow + bp * 32 + 32);
      const int j0 = bp * 32 + (g << 2), j1 = j0 + 32;
      acc0 += g0.x * ds[j0] + g0.y * ds[j0 + 1] + g0.z * ds[j0 + 2] + g0.w * ds[j0 + 3];
      acc1 += g1.x * ds[j1] + g1.y * ds[j1 + 1] + g1.z * ds[j1 + 2] + g1.w * ds[j1 + 3];
    }
    if (bp < blk) {
      const float4 gv = *(const float4*)(grow + bp * 32);
      const int j = bp * 32 + (g << 2);
      acc0 += gv.x * ds[j] + gv.y * ds[j + 1] + gv.z * ds[j + 2] + gv.w * ds[j + 3];
    }
    part[i][g] = acc0 + acc1;
    __syncthreads();
    if (tid < 32) {
      const float c = part[tid][0] + part[tid][1] + part[tid][2] + part[tid][3] +
                      part[tid][4] + part[tid][5] + part[tid][6] + part[tid][7];
      rhs[tid] = pb[blk * 32 + tid] - CF * c;
      // wave-synchronous: LDS write then read within one wave (no barrier)
      const float* wrow = Wsol + ((long)(b * NB + blk) << 10) + tid * 32;
      float dv = 0.0f;
#pragma unroll
      for (int k = 0; k < 32; k += 4) {
        const float4 wv = *(const float4*)(wrow + k);
        dv += wv.x * rhs[k] + wv.y * rhs[k + 1] + wv.z * rhs[k + 2] + wv.w * rhs[k + 3];
      }
      if (blk == NB - 1 && tid == 31) dv = 0.0f;   // dummy s=511
      ds[blk * 32 + tid] = dv;
      d_all[(long)b * 512 + blk * 32 + tid] = dv;
    }
    __syncthreads();
  }
}

// ---------------------------------------------------------------------------
// FUSED m accumulation + readout projection. Grid 8 (one block per batch).
// Wave w strides t by 4; lane covers 4 channels (float4). LDS combine, then
// r = (CF * m) @ Wrp + brp.
// ---------------------------------------------------------------------------
__global__ __launch_bounds__(256) void k_mrp2(
    const float* __restrict__ h, const float* __restrict__ d_all,
    const float* __restrict__ Wrp, const float* __restrict__ brp,
    float* __restrict__ r)
{
  __shared__ float acc_s[4][Hz];
  __shared__ float ms[Hz];
  const int b = blockIdx.x, tid = threadIdx.x;
  const int w = tid >> 6, lane = tid & 63;
  const float* hb = h + (long)b * Lz * Hz;
  const float* db = d_all + ((long)b << 9);
  const int off = lane << 2;
  float4 acc = {0.f, 0.f, 0.f, 0.f};
  for (int t = w; t < 511; t += 4) {
    const float dv = db[510 - t];
    const float4 hv = *(const float4*)(hb + (long)t * Hz + off);
    acc.x = fmaf(dv, hv.x, acc.x); acc.y = fmaf(dv, hv.y, acc.y);
    acc.z = fmaf(dv, hv.z, acc.z); acc.w = fmaf(dv, hv.w, acc.w);
  }
  *(float4*)&acc_s[w][off] = acc;
  __syncthreads();
  ms[tid] = CF * (acc_s[0][tid] + acc_s[1][tid] + acc_s[2][tid] + acc_s[3][tid]);
  __syncthreads();
  float racc = 0.0f;
#pragma unroll 8
  for (int e = 0; e < Hz; ++e)
    racc = fmaf(ms[e], Wrp[(long)e * Hz + tid], racc);
  r[b * Hz + tid] = racc + brp[tid];
}

// ---------------------------------------------------------------------------
// out[8,32000] = r[8,256] @ Wout[256,32000] + bout.
// ---------------------------------------------------------------------------
__global__ __launch_bounds__(256) void k_outproj(
    const float* __restrict__ r, const float* __restrict__ Wout,
    const float* __restrict__ bout, float* __restrict__ out)
{
  __shared__ float rs[8 * Hz];
  __shared__ float part[4][8][64];
  const int tid = threadIdx.x, w = tid >> 6, lane = tid & 63;
  ((float4*)rs)[tid * 2 + 0] = ((const float4*)r)[tid * 2 + 0];
  ((float4*)rs)[tid * 2 + 1] = ((const float4*)r)[tid * 2 + 1];
  __syncthreads();
  const int col = blockIdx.x * 64 + lane;
  float acc[8] = {};
  const int i0 = w << 6;
#pragma unroll 8
  for (int ii = 0; ii < 64; ++ii) {
    const int i = i0 + ii;
    const float wv = Wout[(long)i * Vz + col];
#pragma unroll
    for (int bb = 0; bb < 8; ++bb) acc[bb] = fmaf(rs[bb * Hz + i], wv, acc[bb]);
  }
#pragma unroll
  for (int bb = 0; bb < 8; ++bb) part[w][bb][lane] = acc[bb];
  __syncthreads();
  const float bo = bout[col];
  float s0 = part[0][w][lane] + part[1][w][lane] + part[2][w][lane] + part[3][w][lane];
  out[(long)w * Vz + col] = s0 + bo;
  const int w4 = w + 4;
  float s1 = part[0][w4][lane] + part[1][w4][lane] + part[2][w4][lane] + part[3][w4][lane];
  out[(long)w4 * Vz + col] = s1 + bo;
}

// ---------------------------------------------------------------------------
extern "C" void kernel_launch(void* const* d_in, const int* in_sizes, int n_in,
                              void* d_out, int out_size, void* d_ws, size_t ws_size,
                              hipStream_t stream)
{
  const int*   seq   = (const int*)  d_in[0];
  const float* embed = (const float*)d_in[1];
  const float* W1    = (const float*)d_in[2];
  const float* b1    = (const float*)d_in[3];
  const float* W2    = (const float*)d_in[4];
  const float* b2    = (const float*)d_in[5];
  const float* gamma = (const float*)d_in[6];
  const float* beta  = (const float*)d_in[7];
  const float* Wrp   = (const float*)d_in[8];
  const float* brp   = (const float*)d_in[9];
  const float* Wout  = (const float*)d_in[10];
  const float* bout  = (const float*)d_in[11];
  float* out = (float*)d_out;

  char* ws = (char*)d_ws;
  const size_t MB = 1024u * 1024u;
  // Temporal overlay: y1bf dies after k_mfma2ln; Gf written by k_gramT (later).
  short* y1bf = (short*)(ws);                        // 4 MB  [0,4)
  float* Gf   = (float*)(ws);                        // 8 MB  [0,8)  (after mfma2ln)
  float* hb   = (float*)(ws + 8 * MB);               // 4 MB
  float* hnb  = (float*)(ws + 12 * MB);              // 4 MB
  short* Knb  = (short*)(ws + 16 * MB);              // 2 MB  bf16 s-order keys
  short* Wt1  = (short*)(ws + 18 * MB);              // 256 KB
  short* Wt2  = (short*)(ws + 18 * MB + 256 * 1024); // 256 KB
  float* Wsol = (float*)(ws + 18 * MB + 512 * 1024); // 512 KB
  float* pbuf = (float*)(ws + 19 * MB);                        // 16 KB
  float* dall = (float*)(ws + 19 * MB + 16 * 1024);            // 16 KB
  float* rb   = (float*)(ws + 19 * MB + 32 * 1024);            // 8 KB

  k_wcvt2<<<64, 256, 0, stream>>>(W1, W2, Wt1, Wt2);
  k_mfma1<<<dim3(H2z / 64, Mz / 64), 256, 0, stream>>>(seq, embed, Wt1, b1, y1bf);
  k_mfma2ln<<<Mz / 16, 256, 0, stream>>>(seq, embed, y1bf, Wt2, b2, gamma, beta,
                                         hb, hnb, Knb);
  k_gramT<<<dim3(8, 8, Bz), 256, 0, stream>>>(Knb, hb, hnb, Gf, Wsol, pbuf);
  k_solve<<<Bz, 256, 0, stream>>>(Gf, pbuf, Wsol, dall);
  k_mrp2<<<Bz, 256, 0, stream>>>(hb, dall, Wrp, brp, rb);
  k_outproj<<<Vz / 64, 256, 0, stream>>>(rb, Wout, bout, out);
}

// Round 3
// 199.683 us; speedup vs baseline: 1.1286x; 1.1286x over previous
//
#include <hip/hip_runtime.h>

// Problem constants
constexpr int Bz  = 8;
constexpr int Lz  = 512;
constexpr int Hz  = 256;
constexpr int H2z = 512;
constexpr int Vz  = 32000;
constexpr int Mz  = Bz * Lz;      // 4096 tokens
constexpr float CF = 0.05f;       // 1 - ALPHA
constexpr int NB  = 16;           // 16 blocks of 32 = 512 (511 real + 1 dummy)

typedef __attribute__((ext_vector_type(8))) short bfrag8;   // 8 bf16
typedef __attribute__((ext_vector_type(4))) float f32x4v;
typedef __attribute__((ext_vector_type(4))) short s4v;

static __device__ __forceinline__ short f2bf(float f) {
  unsigned u = __builtin_bit_cast(unsigned, f);
  u += 0x7fffu + ((u >> 16) & 1u);           // round-to-nearest-even
  return (short)(u >> 16);
}

// ---------------------------------------------------------------------------
// Weight transpose+convert, both W1 and W2 in one launch. dst[n][k]=bf16(src[k][n])
// ---------------------------------------------------------------------------
static __device__ __forceinline__ void wcvt_tile(
    const float* __restrict__ src, short* __restrict__ dst,
    int K, int N, int n0, int k0, int tid)
{
  __shared__ float tile[64][68];
  const int rr = tid >> 4, c4 = (tid & 15) << 2;
#pragma unroll
  for (int q = 0; q < 4; ++q) {
    const int kr = rr + q * 16;
    *(float4*)&tile[kr][c4] = *(const float4*)(src + (long)(k0 + kr) * N + n0 + c4);
  }
  __syncthreads();
#pragma unroll
  for (int q = 0; q < 4; ++q) {
    const int nr = rr + q * 16;
    s4v o = { f2bf(tile[c4 + 0][nr]), f2bf(tile[c4 + 1][nr]),
              f2bf(tile[c4 + 2][nr]), f2bf(tile[c4 + 3][nr]) };
    *(s4v*)(dst + (long)(n0 + nr) * K + k0 + c4) = o;
  }
}

__global__ __launch_bounds__(256) void k_wcvt2(
    const float* __restrict__ W1, const float* __restrict__ W2,
    short* __restrict__ Wt1, short* __restrict__ Wt2)
{
  const int bx = blockIdx.x, tid = threadIdx.x;
  if (bx < 32) {
    wcvt_tile(W1, Wt1, Hz, H2z, (bx & 7) * 64, (bx >> 3) * 64, tid);
  } else {
    const int b2 = bx - 32;
    wcvt_tile(W2, Wt2, H2z, Hz, (b2 & 3) * 64, (b2 >> 2) * 64, tid);
  }
}

// ---------------------------------------------------------------------------
// MFMA GEMM1 with fused embedding gather:
// y1bf[4096,512] = bf16(relu(bf16(embed[seq]) @ Wt1^T + b1))
// ---------------------------------------------------------------------------
__global__ __launch_bounds__(256) void k_mfma1(
    const int* __restrict__ seq, const float* __restrict__ embed,
    const short* __restrict__ Wt1, const float* __restrict__ b1,
    short* __restrict__ y1bf)
{
  __shared__ short As[64][32];
  __shared__ short Bs[64][32];
  const int tid = threadIdx.x;
  const int n0 = blockIdx.x * 64, m0 = blockIdx.y * 64;
  const int w = tid >> 6, l = tid & 63;
  const int srow = tid >> 2, skq = (tid & 3) << 3;
  const long abase = (long)seq[m0 + srow] * Hz;
  const f32x4v zero = {0.f, 0.f, 0.f, 0.f};
  f32x4v acc[4] = {zero, zero, zero, zero};
  for (int kc = 0; kc < Hz; kc += 32) {
    const float4 a0 = *(const float4*)(embed + abase + kc + skq);
    const float4 a1 = *(const float4*)(embed + abase + kc + skq + 4);
    const bfrag8 bvl = *(const bfrag8*)(Wt1 + (long)(n0 + srow) * Hz + kc + skq);
    __syncthreads();
    bfrag8 av = { f2bf(a0.x), f2bf(a0.y), f2bf(a0.z), f2bf(a0.w),
                  f2bf(a1.x), f2bf(a1.y), f2bf(a1.z), f2bf(a1.w) };
    *(bfrag8*)&As[srow][skq] = av;
    *(bfrag8*)&Bs[srow][skq] = bvl;
    __syncthreads();
    const bfrag8 a = *(const bfrag8*)&As[(w << 4) + (l & 15)][(l >> 4) << 3];
#pragma unroll
    for (int nn = 0; nn < 4; ++nn) {
      const bfrag8 bb = *(const bfrag8*)&Bs[(nn << 4) + (l & 15)][(l >> 4) << 3];
      acc[nn] = __builtin_amdgcn_mfma_f32_16x16x32_bf16(a, bb, acc[nn], 0, 0, 0);
    }
  }
  const int col0 = l & 15, quad = l >> 4;
#pragma unroll
  for (int nn = 0; nn < 4; ++nn) {
    const int col = n0 + (nn << 4) + col0;
    const float bias = b1[col];
#pragma unroll
    for (int i = 0; i < 4; ++i) {
      const int row = m0 + (w << 4) + (quad << 2) + i;
      y1bf[(long)row * H2z + col] = f2bf(fmaxf(acc[nn][i] + bias, 0.0f));
    }
  }
}

// ---------------------------------------------------------------------------
// FUSED GEMM2 + residual + LayerNorm + L2-normalize, full-occupancy version.
// Grid: 256 blocks x 16 rows. 4 waves split the 256 cols (64 each, 4 frags).
// LN row stats reduced in-quad then combined across the 4 waves via LDS.
// Writes h (fp32 t-order), hn (fp32 t-order), Knb (bf16 s-order, row 511 zero).
// ---------------------------------------------------------------------------
__global__ __launch_bounds__(256) void k_mfma2ln(
    const int* __restrict__ seq, const float* __restrict__ embed,
    const short* __restrict__ y1bf, const short* __restrict__ Wt2,
    const float* __restrict__ b2, const float* __restrict__ gamma,
    const float* __restrict__ beta, float* __restrict__ h,
    float* __restrict__ hn, short* __restrict__ Knb)
{
  __shared__ short As[16][32];     // 1 KB
  __shared__ short Bs[256][32];    // 16 KB (all 256 output cols of Wt2)
  __shared__ float red[4][16][2];  // per-wave LN partials (s, ss)
  __shared__ float red2[4][16];    // per-wave L2 partials
  const int tid = threadIdx.x;
  const int m0 = blockIdx.x * 16;
  const int w = tid >> 6, l = tid & 63;
  const int srow = tid >> 2, skq = (tid & 3) << 3;
  const f32x4v zero = {0.f, 0.f, 0.f, 0.f};
  f32x4v acc[4] = {zero, zero, zero, zero};

  for (int kc = 0; kc < H2z; kc += 32) {
    // issue global loads before the barrier (hide latency under prior MFMA)
    bfrag8 av = {};
    if (tid < 64)
      av = *(const bfrag8*)(y1bf + (long)(m0 + (tid >> 2)) * H2z + kc + skq);
    bfrag8 bv[4];
#pragma unroll
    for (int q = 0; q < 4; ++q)
      bv[q] = *(const bfrag8*)(Wt2 + (long)(srow + (q << 6)) * H2z + kc + skq);
    __syncthreads();
    if (tid < 64) *(bfrag8*)&As[tid >> 2][skq] = av;
#pragma unroll
    for (int q = 0; q < 4; ++q)
      *(bfrag8*)&Bs[srow + (q << 6)][skq] = bv[q];
    __syncthreads();
    const bfrag8 a = *(const bfrag8*)&As[l & 15][(l >> 4) << 3];
#pragma unroll
    for (int nn = 0; nn < 4; ++nn) {
      const bfrag8 bb = *(const bfrag8*)&Bs[(w << 6) + (nn << 4) + (l & 15)][(l >> 4) << 3];
      acc[nn] = __builtin_amdgcn_mfma_f32_16x16x32_bf16(a, bb, acc[nn], 0, 0, 0);
    }
  }

  const int col0 = l & 15, quad = l >> 4;
  float g_r[4], be_r[4], b2_r[4];
#pragma unroll
  for (int nn = 0; nn < 4; ++nn) {
    const int col = (w << 6) + (nn << 4) + col0;
    g_r[nn] = gamma[col]; be_r[nn] = beta[col]; b2_r[nn] = b2[col];
  }

  // pass 1: residual add, per-row mean/var partials (this wave's 64 cols)
  float v[4][4];                    // [i][nn]
#pragma unroll
  for (int i = 0; i < 4; ++i) {
    const int lr = (quad << 2) + i;
    const int row = m0 + lr;
    const long ebase = (long)seq[row] * Hz;
    float s = 0.0f, ss = 0.0f;
#pragma unroll
    for (int nn = 0; nn < 4; ++nn) {
      const int col = (w << 6) + (nn << 4) + col0;
      const float t = acc[nn][i] + b2_r[nn] + embed[ebase + col];
      v[i][nn] = t; s += t; ss += t * t;
    }
#pragma unroll
    for (int o = 8; o >= 1; o >>= 1) { s += __shfl_xor(s, o); ss += __shfl_xor(ss, o); }
    if ((l & 15) == 0) { red[w][lr][0] = s; red[w][lr][1] = ss; }
  }
  __syncthreads();

  // pass 2: LN normalize, per-row L2 partials
#pragma unroll
  for (int i = 0; i < 4; ++i) {
    const int lr = (quad << 2) + i;
    const float s  = red[0][lr][0] + red[1][lr][0] + red[2][lr][0] + red[3][lr][0];
    const float ss = red[0][lr][1] + red[1][lr][1] + red[2][lr][1] + red[3][lr][1];
    const float mu   = s * (1.0f / Hz);
    const float var  = ss * (1.0f / Hz) - mu * mu;
    const float rstd = rsqrtf(var + 1e-5f);
    float hs = 0.0f;
#pragma unroll
    for (int nn = 0; nn < 4; ++nn) {
      const float hv = (v[i][nn] - mu) * rstd * g_r[nn] + be_r[nn];
      v[i][nn] = hv; hs += hv * hv;
    }
#pragma unroll
    for (int o = 8; o >= 1; o >>= 1) hs += __shfl_xor(hs, o);
    if ((l & 15) == 0) red2[w][lr] = hs;
  }
  __syncthreads();

  // pass 3: L2 normalize + stores
#pragma unroll
  for (int i = 0; i < 4; ++i) {
    const int lr = (quad << 2) + i;
    const float hs = red2[0][lr] + red2[1][lr] + red2[2][lr] + red2[3][lr];
    const float inv = 1.0f / fmaxf(sqrtf(hs), 1e-12f);
    const int row = m0 + lr;
    float* hrow  = h  + (long)row * Hz;
    float* hnrow = hn + (long)row * Hz;
    const int bb_ = row >> 9, t = row & 511;
    short* kr = Knb + ((long)bb_ * 512 + (t < 511 ? 510 - t : 511)) * Hz;
#pragma unroll
    for (int nn = 0; nn < 4; ++nn) {
      const int col = (w << 6) + (nn << 4) + col0;
      const float hv = v[i][nn];
      const float nv = hv * inv;
      hrow[col]  = hv;
      hnrow[col] = nv;
      kr[col] = (t < 511) ? f2bf(nv) : (short)0;
    }
  }
}

// ---------------------------------------------------------------------------
// Full Gram via bf16 MFMA (lower tiles), with FUSED block-diag inverse
// (one wave per 32x32 diag block) AND fused p computation: 16 of the idle
// upper-triangle blocks per batch each compute 32 entries of
// p[b][s] = hn[b][510-s] . h[b][511], concurrently with the Gram tiles.
// ---------------------------------------------------------------------------
__global__ __launch_bounds__(256) void k_gramT(
    const short* __restrict__ Knb, const float* __restrict__ h,
    const float* __restrict__ hn, float* __restrict__ G,
    float* __restrict__ Wsol, float* __restrict__ p)
{
  const int nb = blockIdx.x, mb = blockIdx.y, b = blockIdx.z;
  __shared__ short As[64][32];
  __shared__ short Bs[64][32];
  __shared__ float Gs2[2][32][33];
  __shared__ float qs[Hz];
  if (nb > mb) {
    // repurposed idle block: p chunk (block-uniform branch, syncthreads legal)
    const int idx = ((nb * (nb - 1)) >> 1) + mb;   // 0..27 upper-tri enumeration
    if (idx >= 16) return;
    const int tid = threadIdx.x;
    qs[tid] = h[((long)b * Lz + 511) * Hz + tid];
    __syncthreads();
    const int s = idx * 32 + (tid >> 3);           // 32 s-rows per block
    const int g = tid & 7;                         // 8 threads per row, 32 ch each
    float acc = 0.0f;
    if (s <= 510) {
      const float* src = hn + ((long)b * Lz + (510 - s)) * Hz + (g << 5);
#pragma unroll
      for (int q = 0; q < 8; ++q) {
        const float4 vv = *(const float4*)(src + 4 * q);
        const int c = (g << 5) + 4 * q;
        acc += vv.x * qs[c] + vv.y * qs[c + 1] + vv.z * qs[c + 2] + vv.w * qs[c + 3];
      }
    }
#pragma unroll
    for (int o = 4; o >= 1; o >>= 1) acc += __shfl_xor(acc, o);
    if (g == 0) p[(long)b * 512 + s] = acc;        // s==511 writes 0 (dummy)
    return;
  }
  const short* Kb = Knb + (long)b * 512 * Hz;
  const int tid = threadIdx.x;
  const int w = tid >> 6, l = tid & 63;
  const int srow = tid >> 2, skq = (tid & 3) << 3;
  const f32x4v zero = {0.f, 0.f, 0.f, 0.f};
  f32x4v acc[4] = {zero, zero, zero, zero};
  for (int kc = 0; kc < Hz; kc += 32) {
    __syncthreads();
    *(bfrag8*)&As[srow][skq] = *(const bfrag8*)(Kb + (long)(mb * 64 + srow) * Hz + kc + skq);
    *(bfrag8*)&Bs[srow][skq] = *(const bfrag8*)(Kb + (long)(nb * 64 + srow) * Hz + kc + skq);
    __syncthreads();
    const bfrag8 a = *(const bfrag8*)&As[(w << 4) + (l & 15)][(l >> 4) << 3];
#pragma unroll
    for (int nn = 0; nn < 4; ++nn) {
      const bfrag8 bb = *(const bfrag8*)&Bs[(nn << 4) + (l & 15)][(l >> 4) << 3];
      acc[nn] = __builtin_amdgcn_mfma_f32_16x16x32_bf16(a, bb, acc[nn], 0, 0, 0);
    }
  }
  const int col0 = l & 15, quad = l >> 4;
  float* Gb = G + (long)b * 512 * 512;
#pragma unroll
  for (int nn = 0; nn < 4; ++nn) {
    const int col = nb * 64 + (nn << 4) + col0;
#pragma unroll
    for (int i = 0; i < 4; ++i) {
      const int row = mb * 64 + (w << 4) + (quad << 2) + i;
      Gb[(long)row * 512 + col] = acc[nn][i];
    }
  }
  if (mb != nb) return;
#pragma unroll
  for (int nn = 0; nn < 4; ++nn) {
    const int lc = (nn << 4) + col0;
#pragma unroll
    for (int i = 0; i < 4; ++i) {
      const int lr = (w << 4) + (quad << 2) + i;
      if ((lr >> 5) == (lc >> 5)) Gs2[lr >> 5][lr & 31][lc & 31] = acc[nn][i];
    }
  }
  __syncthreads();
  if (w < 2 && l < 32) {       // wave w inverts sub-block w; lane = column c
    const int c = l;
    float wv[32];
    wv[0] = (c == 0) ? 1.0f : 0.0f;
#pragma unroll
    for (int i = 1; i < 32; ++i) {
      float sum = 0.0f;
#pragma unroll
      for (int j = 0; j < i; ++j) sum = fmaf(Gs2[w][i][j], wv[j], sum);
      wv[i] = ((i == c) ? 1.0f : 0.0f) - CF * sum;
    }
    const int blk = mb * 2 + w;
    float* dst = Wsol + ((long)(b * NB + blk) << 10) + c;
#pragma unroll
    for (int i = 0; i < 32; ++i) dst[i * 32] = wv[i];
  }
}

// ---------------------------------------------------------------------------
// Block-triangular solve — only the truly-serial chain. 8 WGs x 256 thr.
// 2 barriers per block-step: off-diag matvec (all threads) -> barrier ->
// wave0 lanes 0-31 do rhs + 32x32 Minv matvec wave-synchronously -> barrier.
// ---------------------------------------------------------------------------
__global__ __launch_bounds__(256) void k_solve(
    const float* __restrict__ G, const float* __restrict__ p,
    const float* __restrict__ Wsol, float* __restrict__ d_all)
{
  __shared__ float ds[512];
  __shared__ float part[32][9];
  __shared__ float rhs[32];
  const int b = blockIdx.x, tid = threadIdx.x;
  const int i = tid >> 3, g = tid & 7;
  const float* Gb = G + (long)b * 512 * 512;
  const float* pb = p + (long)b * 512;

  for (int blk = 0; blk < NB; ++blk) {
    float acc0 = 0.0f, acc1 = 0.0f;
    const float* grow = Gb + (long)(blk * 32 + i) * 512 + (g << 2);
    int bp = 0;
    for (; bp + 1 < blk; bp += 2) {
      const float4 g0 = *(const float4*)(grow + bp * 32);
      const float4 g1 = *(const float4*)(grow + bp * 32 + 32);
      const int j0 = bp * 32 + (g << 2), j1 = j0 + 32;
      acc0 += g0.x * ds[j0] + g0.y * ds[j0 + 1] + g0.z * ds[j0 + 2] + g0.w * ds[j0 + 3];
      acc1 += g1.x * ds[j1] + g1.y * ds[j1 + 1] + g1.z * ds[j1 + 2] + g1.w * ds[j1 + 3];
    }
    if (bp < blk) {
      const float4 gv = *(const float4*)(grow + bp * 32);
      const int j = bp * 32 + (g << 2);
      acc0 += gv.x * ds[j] + gv.y * ds[j + 1] + gv.z * ds[j + 2] + gv.w * ds[j + 3];
    }
    part[i][g] = acc0 + acc1;
    __syncthreads();
    if (tid < 32) {
      const float c = part[tid][0] + part[tid][1] + part[tid][2] + part[tid][3] +
                      part[tid][4] + part[tid][5] + part[tid][6] + part[tid][7];
      rhs[tid] = pb[blk * 32 + tid] - CF * c;
      // wave-synchronous: LDS write then read within one wave (no barrier)
      const float* wrow = Wsol + ((long)(b * NB + blk) << 10) + tid * 32;
      float dv = 0.0f;
#pragma unroll
      for (int k = 0; k < 32; k += 4) {
        const float4 wv = *(const float4*)(wrow + k);
        dv += wv.x * rhs[k] + wv.y * rhs[k + 1] + wv.z * rhs[k + 2] + wv.w * rhs[k + 3];
      }
      if (blk == NB - 1 && tid == 31) dv = 0.0f;   // dummy s=511
      ds[blk * 32 + tid] = dv;
      d_all[(long)b * 512 + blk * 32 + tid] = dv;
    }
    __syncthreads();
  }
}

// ---------------------------------------------------------------------------
// m partials, float4-vectorized: chunk c covers 16 t; wave w handles
// t = t0 + {w, w+4, w+8, w+12}; lane loads dwordx4 of the h row.
// part[b][c][:] accumulated across the 4 waves via LDS.
// 256 blocks — full-occupancy version (grid-8 fusion was latency-bound: 46 us).
// ---------------------------------------------------------------------------
__global__ __launch_bounds__(256) void k_mrp(
    const float* __restrict__ h, const float* __restrict__ d_all,
    float* __restrict__ part)
{
  __shared__ float acc_s[4][Hz];
  const int c = blockIdx.x, b = blockIdx.y, tid = threadIdx.x;
  const int w = tid >> 6, lane = tid & 63;
  const float* hb = h + (long)b * Lz * Hz;
  const float* db = d_all + ((long)b << 9);
  const int t0 = c * 16;
  const int off = lane << 2;
  float4 acc = {0.f, 0.f, 0.f, 0.f};
#pragma unroll
  for (int q = 0; q < 4; ++q) {
    const int t = t0 + (q << 2) + w;
    if (t < 511) {
      const float dv = db[510 - t];
      const float4 hv = *(const float4*)(hb + (long)t * Hz + off);
      acc.x = fmaf(dv, hv.x, acc.x); acc.y = fmaf(dv, hv.y, acc.y);
      acc.z = fmaf(dv, hv.z, acc.z); acc.w = fmaf(dv, hv.w, acc.w);
    }
  }
  *(float4*)&acc_s[w][off] = acc;
  __syncthreads();
  if (tid < Hz) {
    part[((long)b * 32 + c) * Hz + tid] =
        acc_s[0][tid] + acc_s[1][tid] + acc_s[2][tid] + acc_s[3][tid];
  }
}

// ---------------------------------------------------------------------------
// Combine partials -> m; r = m @ Wrp + brp.  8 WGs.
// ---------------------------------------------------------------------------
__global__ __launch_bounds__(256) void k_mr2(
    const float* __restrict__ part, const float* __restrict__ Wrp,
    const float* __restrict__ brp, float* __restrict__ r)
{
  __shared__ float ms[Hz];
  const int b = blockIdx.x, tid = threadIdx.x;
  float acc = 0.0f;
#pragma unroll
  for (int c = 0; c < 32; ++c) acc += part[((long)b * 32 + c) * Hz + tid];
  ms[tid] = CF * acc;
  __syncthreads();
  float racc = 0.0f;
#pragma unroll 8
  for (int e = 0; e < Hz; ++e)
    racc = fmaf(ms[e], Wrp[(long)e * Hz + tid], racc);
  r[b * Hz + tid] = racc + brp[tid];
}

// ---------------------------------------------------------------------------
// out[8,32000] = r[8,256] @ Wout[256,32000] + bout.
// ---------------------------------------------------------------------------
__global__ __launch_bounds__(256) void k_outproj(
    const float* __restrict__ r, const float* __restrict__ Wout,
    const float* __restrict__ bout, float* __restrict__ out)
{
  __shared__ float rs[8 * Hz];
  __shared__ float part[4][8][64];
  const int tid = threadIdx.x, w = tid >> 6, lane = tid & 63;
  ((float4*)rs)[tid * 2 + 0] = ((const float4*)r)[tid * 2 + 0];
  ((float4*)rs)[tid * 2 + 1] = ((const float4*)r)[tid * 2 + 1];
  __syncthreads();
  const int col = blockIdx.x * 64 + lane;
  float acc[8] = {};
  const int i0 = w << 6;
#pragma unroll 8
  for (int ii = 0; ii < 64; ++ii) {
    const int i = i0 + ii;
    const float wv = Wout[(long)i * Vz + col];
#pragma unroll
    for (int bb = 0; bb < 8; ++bb) acc[bb] = fmaf(rs[bb * Hz + i], wv, acc[bb]);
  }
#pragma unroll
  for (int bb = 0; bb < 8; ++bb) part[w][bb][lane] = acc[bb];
  __syncthreads();
  const float bo = bout[col];
  float s0 = part[0][w][lane] + part[1][w][lane] + part[2][w][lane] + part[3][w][lane];
  out[(long)w * Vz + col] = s0 + bo;
  const int w4 = w + 4;
  float s1 = part[0][w4][lane] + part[1][w4][lane] + part[2][w4][lane] + part[3][w4][lane];
  out[(long)w4 * Vz + col] = s1 + bo;
}

// ---------------------------------------------------------------------------
extern "C" void kernel_launch(void* const* d_in, const int* in_sizes, int n_in,
                              void* d_out, int out_size, void* d_ws, size_t ws_size,
                              hipStream_t stream)
{
  const int*   seq   = (const int*)  d_in[0];
  const float* embed = (const float*)d_in[1];
  const float* W1    = (const float*)d_in[2];
  const float* b1    = (const float*)d_in[3];
  const float* W2    = (const float*)d_in[4];
  const float* b2    = (const float*)d_in[5];
  const float* gamma = (const float*)d_in[6];
  const float* beta  = (const float*)d_in[7];
  const float* Wrp   = (const float*)d_in[8];
  const float* brp   = (const float*)d_in[9];
  const float* Wout  = (const float*)d_in[10];
  const float* bout  = (const float*)d_in[11];
  float* out = (float*)d_out;

  char* ws = (char*)d_ws;
  const size_t MB = 1024u * 1024u;
  // Temporal overlay: y1bf dies after k_mfma2ln; Gf written by k_gramT (later).
  short* y1bf = (short*)(ws);                        // 4 MB  [0,4)
  float* Gf   = (float*)(ws);                        // 8 MB  [0,8)  (after mfma2ln)
  float* hb   = (float*)(ws + 8 * MB);               // 4 MB
  float* hnb  = (float*)(ws + 12 * MB);              // 4 MB
  short* Knb  = (short*)(ws + 16 * MB);              // 2 MB  bf16 s-order keys
  short* Wt1  = (short*)(ws + 18 * MB);              // 256 KB
  short* Wt2  = (short*)(ws + 18 * MB + 256 * 1024); // 256 KB
  float* Wsol = (float*)(ws + 18 * MB + 512 * 1024); // 512 KB
  float* pbuf = (float*)(ws + 19 * MB);                        // 16 KB
  float* dall = (float*)(ws + 19 * MB + 16 * 1024);            // 16 KB
  float* prt  = (float*)(ws + 19 * MB + 32 * 1024);            // 256 KB
  float* rb   = (float*)(ws + 19 * MB + 288 * 1024);           // 8 KB

  k_wcvt2<<<64, 256, 0, stream>>>(W1, W2, Wt1, Wt2);
  k_mfma1<<<dim3(H2z / 64, Mz / 64), 256, 0, stream>>>(seq, embed, Wt1, b1, y1bf);
  k_mfma2ln<<<Mz / 16, 256, 0, stream>>>(seq, embed, y1bf, Wt2, b2, gamma, beta,
                                         hb, hnb, Knb);
  k_gramT<<<dim3(8, 8, Bz), 256, 0, stream>>>(Knb, hb, hnb, Gf, Wsol, pbuf);
  k_solve<<<Bz, 256, 0, stream>>>(Gf, pbuf, Wsol, dall);
  k_mrp<<<dim3(32, Bz), 256, 0, stream>>>(hb, dall, prt);
  k_mr2<<<Bz, 256, 0, stream>>>(prt, Wrp, brp, rb);
  k_outproj<<<Vz / 64, 256, 0, stream>>>(rb, Wout, bout, out);
}

// Round 4
// 177.584 us; speedup vs baseline: 1.2691x; 1.1244x over previous
//
#include <hip/hip_runtime.h>

// Problem constants
constexpr int Bz  = 8;
constexpr int Lz  = 512;
constexpr int Hz  = 256;
constexpr int H2z = 512;
constexpr int Vz  = 32000;
constexpr int Mz  = Bz * Lz;      // 4096 tokens
constexpr float CF = 0.05f;       // 1 - ALPHA
constexpr int NB  = 16;           // 16 blocks of 32 = 512 (511 real + 1 dummy)

typedef __attribute__((ext_vector_type(8))) short bfrag8;   // 8 bf16
typedef __attribute__((ext_vector_type(4))) float f32x4v;
typedef __attribute__((ext_vector_type(4))) short s4v;

static __device__ __forceinline__ short f2bf(float f) {
  unsigned u = __builtin_bit_cast(unsigned, f);
  u += 0x7fffu + ((u >> 16) & 1u);           // round-to-nearest-even
  return (short)(u >> 16);
}

// ---------------------------------------------------------------------------
// Weight transpose+convert + embedding gather->bf16, one launch.
// blocks [0,32): W1 tiles; [32,64): W2 tiles; [64,320): Eg gather.
// ---------------------------------------------------------------------------
static __device__ __forceinline__ void wcvt_tile(
    const float* __restrict__ src, short* __restrict__ dst,
    int K, int N, int n0, int k0, int tid)
{
  __shared__ float tile[64][68];
  const int rr = tid >> 4, c4 = (tid & 15) << 2;
#pragma unroll
  for (int q = 0; q < 4; ++q) {
    const int kr = rr + q * 16;
    *(float4*)&tile[kr][c4] = *(const float4*)(src + (long)(k0 + kr) * N + n0 + c4);
  }
  __syncthreads();
#pragma unroll
  for (int q = 0; q < 4; ++q) {
    const int nr = rr + q * 16;
    s4v o = { f2bf(tile[c4 + 0][nr]), f2bf(tile[c4 + 1][nr]),
              f2bf(tile[c4 + 2][nr]), f2bf(tile[c4 + 3][nr]) };
    *(s4v*)(dst + (long)(n0 + nr) * K + k0 + c4) = o;
  }
}

__global__ __launch_bounds__(256) void k_wcvt2(
    const float* __restrict__ W1, const float* __restrict__ W2,
    const int* __restrict__ seq, const float* __restrict__ embed,
    short* __restrict__ Wt1, short* __restrict__ Wt2, short* __restrict__ Eg)
{
  const int bx = blockIdx.x, tid = threadIdx.x;
  if (bx < 32) {
    wcvt_tile(W1, Wt1, Hz, H2z, (bx & 7) * 64, (bx >> 3) * 64, tid);
  } else if (bx < 64) {
    const int b2 = bx - 32;
    wcvt_tile(W2, Wt2, H2z, Hz, (b2 & 3) * 64, (b2 >> 2) * 64, tid);
  } else {
    // Eg[row][:] = bf16(embed[seq[row]][:]), 16 rows per block
    const int row = (bx - 64) * 16 + (tid >> 4);
    const int c0 = (tid & 15) << 4;
    const long src = (long)seq[row] * Hz + c0;
    const float4 v0 = *(const float4*)(embed + src);
    const float4 v1 = *(const float4*)(embed + src + 4);
    const float4 v2 = *(const float4*)(embed + src + 8);
    const float4 v3 = *(const float4*)(embed + src + 12);
    bfrag8 o0 = { f2bf(v0.x), f2bf(v0.y), f2bf(v0.z), f2bf(v0.w),
                  f2bf(v1.x), f2bf(v1.y), f2bf(v1.z), f2bf(v1.w) };
    bfrag8 o1 = { f2bf(v2.x), f2bf(v2.y), f2bf(v2.z), f2bf(v2.w),
                  f2bf(v3.x), f2bf(v3.y), f2bf(v3.z), f2bf(v3.w) };
    *(bfrag8*)(Eg + (long)row * Hz + c0) = o0;
    *(bfrag8*)(Eg + (long)row * Hz + c0 + 8) = o1;
  }
}

// ---------------------------------------------------------------------------
// MFMA GEMM1: y1bf[4096,512] = bf16(relu(Eg @ Wt1^T + b1)); Eg pre-gathered bf16.
// ---------------------------------------------------------------------------
__global__ __launch_bounds__(256) void k_mfma1(
    const short* __restrict__ Eg, const short* __restrict__ Wt1,
    const float* __restrict__ b1, short* __restrict__ y1bf)
{
  __shared__ short As[64][32];
  __shared__ short Bs[64][32];
  const int tid = threadIdx.x;
  const int n0 = blockIdx.x * 64, m0 = blockIdx.y * 64;
  const int w = tid >> 6, l = tid & 63;
  const int srow = tid >> 2, skq = (tid & 3) << 3;
  const f32x4v zero = {0.f, 0.f, 0.f, 0.f};
  f32x4v acc[4] = {zero, zero, zero, zero};
  for (int kc = 0; kc < Hz; kc += 32) {
    const bfrag8 avl = *(const bfrag8*)(Eg + (long)(m0 + srow) * Hz + kc + skq);
    const bfrag8 bvl = *(const bfrag8*)(Wt1 + (long)(n0 + srow) * Hz + kc + skq);
    __syncthreads();
    *(bfrag8*)&As[srow][skq] = avl;
    *(bfrag8*)&Bs[srow][skq] = bvl;
    __syncthreads();
    const bfrag8 a = *(const bfrag8*)&As[(w << 4) + (l & 15)][(l >> 4) << 3];
#pragma unroll
    for (int nn = 0; nn < 4; ++nn) {
      const bfrag8 bb = *(const bfrag8*)&Bs[(nn << 4) + (l & 15)][(l >> 4) << 3];
      acc[nn] = __builtin_amdgcn_mfma_f32_16x16x32_bf16(a, bb, acc[nn], 0, 0, 0);
    }
  }
  const int col0 = l & 15, quad = l >> 4;
#pragma unroll
  for (int nn = 0; nn < 4; ++nn) {
    const int col = n0 + (nn << 4) + col0;
    const float bias = b1[col];
#pragma unroll
    for (int i = 0; i < 4; ++i) {
      const int row = m0 + (w << 4) + (quad << 2) + i;
      y1bf[(long)row * H2z + col] = f2bf(fmaxf(acc[nn][i] + bias, 0.0f));
    }
  }
}

// ---------------------------------------------------------------------------
// FUSED GEMM2 + residual + LayerNorm + L2-normalize, full-occupancy version.
// Grid: 256 blocks x 16 rows. 4 waves split the 256 cols (64 each, 4 frags).
// ---------------------------------------------------------------------------
__global__ __launch_bounds__(256) void k_mfma2ln(
    const int* __restrict__ seq, const float* __restrict__ embed,
    const short* __restrict__ y1bf, const short* __restrict__ Wt2,
    const float* __restrict__ b2, const float* __restrict__ gamma,
    const float* __restrict__ beta, float* __restrict__ h,
    float* __restrict__ hn, short* __restrict__ Knb)
{
  __shared__ short As[16][32];     // 1 KB
  __shared__ short Bs[256][32];    // 16 KB (all 256 output cols of Wt2)
  __shared__ float red[4][16][2];  // per-wave LN partials (s, ss)
  __shared__ float red2[4][16];    // per-wave L2 partials
  const int tid = threadIdx.x;
  const int m0 = blockIdx.x * 16;
  const int w = tid >> 6, l = tid & 63;
  const int srow = tid >> 2, skq = (tid & 3) << 3;
  const f32x4v zero = {0.f, 0.f, 0.f, 0.f};
  f32x4v acc[4] = {zero, zero, zero, zero};

  for (int kc = 0; kc < H2z; kc += 32) {
    bfrag8 av = {};
    if (tid < 64)
      av = *(const bfrag8*)(y1bf + (long)(m0 + (tid >> 2)) * H2z + kc + skq);
    bfrag8 bv[4];
#pragma unroll
    for (int q = 0; q < 4; ++q)
      bv[q] = *(const bfrag8*)(Wt2 + (long)(srow + (q << 6)) * H2z + kc + skq);
    __syncthreads();
    if (tid < 64) *(bfrag8*)&As[tid >> 2][skq] = av;
#pragma unroll
    for (int q = 0; q < 4; ++q)
      *(bfrag8*)&Bs[srow + (q << 6)][skq] = bv[q];
    __syncthreads();
    const bfrag8 a = *(const bfrag8*)&As[l & 15][(l >> 4) << 3];
#pragma unroll
    for (int nn = 0; nn < 4; ++nn) {
      const bfrag8 bb = *(const bfrag8*)&Bs[(w << 6) + (nn << 4) + (l & 15)][(l >> 4) << 3];
      acc[nn] = __builtin_amdgcn_mfma_f32_16x16x32_bf16(a, bb, acc[nn], 0, 0, 0);
    }
  }

  const int col0 = l & 15, quad = l >> 4;
  float g_r[4], be_r[4], b2_r[4];
#pragma unroll
  for (int nn = 0; nn < 4; ++nn) {
    const int col = (w << 6) + (nn << 4) + col0;
    g_r[nn] = gamma[col]; be_r[nn] = beta[col]; b2_r[nn] = b2[col];
  }

  // pass 1: residual add, per-row mean/var partials (this wave's 64 cols)
  float v[4][4];                    // [i][nn]
#pragma unroll
  for (int i = 0; i < 4; ++i) {
    const int lr = (quad << 2) + i;
    const int row = m0 + lr;
    const long ebase = (long)seq[row] * Hz;
    float s = 0.0f, ss = 0.0f;
#pragma unroll
    for (int nn = 0; nn < 4; ++nn) {
      const int col = (w << 6) + (nn << 4) + col0;
      const float t = acc[nn][i] + b2_r[nn] + embed[ebase + col];
      v[i][nn] = t; s += t; ss += t * t;
    }
#pragma unroll
    for (int o = 8; o >= 1; o >>= 1) { s += __shfl_xor(s, o); ss += __shfl_xor(ss, o); }
    if ((l & 15) == 0) { red[w][lr][0] = s; red[w][lr][1] = ss; }
  }
  __syncthreads();

  // pass 2: LN normalize, per-row L2 partials
#pragma unroll
  for (int i = 0; i < 4; ++i) {
    const int lr = (quad << 2) + i;
    const float s  = red[0][lr][0] + red[1][lr][0] + red[2][lr][0] + red[3][lr][0];
    const float ss = red[0][lr][1] + red[1][lr][1] + red[2][lr][1] + red[3][lr][1];
    const float mu   = s * (1.0f / Hz);
    const float var  = ss * (1.0f / Hz) - mu * mu;
    const float rstd = rsqrtf(var + 1e-5f);
    float hs = 0.0f;
#pragma unroll
    for (int nn = 0; nn < 4; ++nn) {
      const float hv = (v[i][nn] - mu) * rstd * g_r[nn] + be_r[nn];
      v[i][nn] = hv; hs += hv * hv;
    }
#pragma unroll
    for (int o = 8; o >= 1; o >>= 1) hs += __shfl_xor(hs, o);
    if ((l & 15) == 0) red2[w][lr] = hs;
  }
  __syncthreads();

  // pass 3: L2 normalize + stores
#pragma unroll
  for (int i = 0; i < 4; ++i) {
    const int lr = (quad << 2) + i;
    const float hs = red2[0][lr] + red2[1][lr] + red2[2][lr] + red2[3][lr];
    const float inv = 1.0f / fmaxf(sqrtf(hs), 1e-12f);
    const int row = m0 + lr;
    float* hrow  = h  + (long)row * Hz;
    float* hnrow = hn + (long)row * Hz;
    const int bb_ = row >> 9, t = row & 511;
    short* kr = Knb + ((long)bb_ * 512 + (t < 511 ? 510 - t : 511)) * Hz;
#pragma unroll
    for (int nn = 0; nn < 4; ++nn) {
      const int col = (w << 6) + (nn << 4) + col0;
      const float hv = v[i][nn];
      const float nv = hv * inv;
      hrow[col]  = hv;
      hnrow[col] = nv;
      kr[col] = (t < 511) ? f2bf(nv) : (short)0;
    }
  }
}

// ---------------------------------------------------------------------------
// Full Gram via bf16 MFMA (lower tiles), with FUSED block-diag inverse
// (one wave per 32x32 diag block) AND fused p computation on idle upper blocks.
// ---------------------------------------------------------------------------
__global__ __launch_bounds__(256) void k_gramT(
    const short* __restrict__ Knb, const float* __restrict__ h,
    const float* __restrict__ hn, float* __restrict__ G,
    float* __restrict__ Wsol, float* __restrict__ p)
{
  const int nb = blockIdx.x, mb = blockIdx.y, b = blockIdx.z;
  __shared__ short As[64][32];
  __shared__ short Bs[64][32];
  __shared__ float Gs2[2][32][33];
  __shared__ float qs[Hz];
  if (nb > mb) {
    // repurposed idle block: p chunk (block-uniform branch, syncthreads legal)
    const int idx = ((nb * (nb - 1)) >> 1) + mb;   // 0..27 upper-tri enumeration
    if (idx >= 16) return;
    const int tid = threadIdx.x;
    qs[tid] = h[((long)b * Lz + 511) * Hz + tid];
    __syncthreads();
    const int s = idx * 32 + (tid >> 3);           // 32 s-rows per block
    const int g = tid & 7;                         // 8 threads per row, 32 ch each
    float acc = 0.0f;
    if (s <= 510) {
      const float* src = hn + ((long)b * Lz + (510 - s)) * Hz + (g << 5);
#pragma unroll
      for (int q = 0; q < 8; ++q) {
        const float4 vv = *(const float4*)(src + 4 * q);
        const int c = (g << 5) + 4 * q;
        acc += vv.x * qs[c] + vv.y * qs[c + 1] + vv.z * qs[c + 2] + vv.w * qs[c + 3];
      }
    }
#pragma unroll
    for (int o = 4; o >= 1; o >>= 1) acc += __shfl_xor(acc, o);
    if (g == 0) p[(long)b * 512 + s] = acc;        // s==511 writes 0 (dummy)
    return;
  }
  const short* Kb = Knb + (long)b * 512 * Hz;
  const int tid = threadIdx.x;
  const int w = tid >> 6, l = tid & 63;
  const int srow = tid >> 2, skq = (tid & 3) << 3;
  const f32x4v zero = {0.f, 0.f, 0.f, 0.f};
  f32x4v acc[4] = {zero, zero, zero, zero};
  for (int kc = 0; kc < Hz; kc += 32) {
    __syncthreads();
    *(bfrag8*)&As[srow][skq] = *(const bfrag8*)(Kb + (long)(mb * 64 + srow) * Hz + kc + skq);
    *(bfrag8*)&Bs[srow][skq] = *(const bfrag8*)(Kb + (long)(nb * 64 + srow) * Hz + kc + skq);
    __syncthreads();
    const bfrag8 a = *(const bfrag8*)&As[(w << 4) + (l & 15)][(l >> 4) << 3];
#pragma unroll
    for (int nn = 0; nn < 4; ++nn) {
      const bfrag8 bb = *(const bfrag8*)&Bs[(nn << 4) + (l & 15)][(l >> 4) << 3];
      acc[nn] = __builtin_amdgcn_mfma_f32_16x16x32_bf16(a, bb, acc[nn], 0, 0, 0);
    }
  }
  const int col0 = l & 15, quad = l >> 4;
  float* Gb = G + (long)b * 512 * 512;
#pragma unroll
  for (int nn = 0; nn < 4; ++nn) {
    const int col = nb * 64 + (nn << 4) + col0;
#pragma unroll
    for (int i = 0; i < 4; ++i) {
      const int row = mb * 64 + (w << 4) + (quad << 2) + i;
      Gb[(long)row * 512 + col] = acc[nn][i];
    }
  }
  if (mb != nb) return;
#pragma unroll
  for (int nn = 0; nn < 4; ++nn) {
    const int lc = (nn << 4) + col0;
#pragma unroll
    for (int i = 0; i < 4; ++i) {
      const int lr = (w << 4) + (quad << 2) + i;
      if ((lr >> 5) == (lc >> 5)) Gs2[lr >> 5][lr & 31][lc & 31] = acc[nn][i];
    }
  }
  __syncthreads();
  if (w < 2 && l < 32) {       // wave w inverts sub-block w; lane = column c
    const int c = l;
    float wv[32];
    wv[0] = (c == 0) ? 1.0f : 0.0f;
#pragma unroll
    for (int i = 1; i < 32; ++i) {
      float sum = 0.0f;
#pragma unroll
      for (int j = 0; j < i; ++j) sum = fmaf(Gs2[w][i][j], wv[j], sum);
      wv[i] = ((i == c) ? 1.0f : 0.0f) - CF * sum;
    }
    const int blk = mb * 2 + w;
    float* dst = Wsol + ((long)(b * NB + blk) << 10) + c;
#pragma unroll
    for (int i = 0; i < 32; ++i) dst[i * 32] = wv[i];
  }
}

// ---------------------------------------------------------------------------
// Block-triangular solve with REGISTER PREFETCH: all G/Wsol/p addresses are
// static (only ds values are dynamic), so step blk+1's operands are loaded
// into registers during step blk — global latency hidden behind the serial
// chain instead of on it. gbuf fully unrolled (compile-time indices only).
// ---------------------------------------------------------------------------
__global__ __launch_bounds__(256) void k_solve(
    const float* __restrict__ G, const float* __restrict__ p,
    const float* __restrict__ Wsol, float* __restrict__ d_all)
{
  __shared__ float ds[512];
  __shared__ float part[32][9];
  __shared__ float rhs[32];
  const int b = blockIdx.x, tid = threadIdx.x;
  const int i = tid >> 3, g = tid & 7;
  const float* Gb = G + (long)b * 512 * 512;
  const float* pb = p + (long)b * 512;

  float4 gbuf[15];                 // G[blk*32+i][bp*32+g*4] for current step
  float4 wbuf[8];                  // wave0: Wsol row for current step
  float  pcur = 0.0f;
  if (tid < 32) {
#pragma unroll
    for (int k = 0; k < 8; ++k)
      wbuf[k] = *(const float4*)(Wsol + ((long)(b * NB) << 10) + tid * 32 + (k << 2));
    pcur = pb[tid];
  }

  for (int blk = 0; blk < NB; ++blk) {
    // off-diagonal matvec using prefetched gbuf (empty at blk=0)
    float acc = 0.0f;
#pragma unroll
    for (int bp = 0; bp < 15; ++bp) {
      if (bp < blk) {
        const int j = bp * 32 + (g << 2);
        acc += gbuf[bp].x * ds[j]     + gbuf[bp].y * ds[j + 1] +
               gbuf[bp].z * ds[j + 2] + gbuf[bp].w * ds[j + 3];
      }
    }
    part[i][g] = acc;
    // issue G prefetch for step blk+1 (independent of ds; hides under barriers)
    if (blk + 1 < NB) {
      const float* grow = Gb + (long)((blk + 1) * 32 + i) * 512 + (g << 2);
#pragma unroll
      for (int bp = 0; bp < 15; ++bp)
        if (bp <= blk) gbuf[bp] = *(const float4*)(grow + bp * 32);
    }
    __syncthreads();
    if (tid < 32) {
      const float c = part[tid][0] + part[tid][1] + part[tid][2] + part[tid][3] +
                      part[tid][4] + part[tid][5] + part[tid][6] + part[tid][7];
      rhs[tid] = pcur - CF * c;
      // wave-synchronous: LDS write then read within one wave (no barrier)
      float dv = 0.0f;
#pragma unroll
      for (int k = 0; k < 8; ++k) {
        const int k0 = k << 2;
        dv += wbuf[k].x * rhs[k0]     + wbuf[k].y * rhs[k0 + 1] +
              wbuf[k].z * rhs[k0 + 2] + wbuf[k].w * rhs[k0 + 3];
      }
      if (blk == NB - 1 && tid == 31) dv = 0.0f;   // dummy s=511
      ds[blk * 32 + tid] = dv;
      d_all[(long)b * 512 + blk * 32 + tid] = dv;
      // prefetch Wsol/p for step blk+1
      if (blk + 1 < NB) {
#pragma unroll
        for (int k = 0; k < 8; ++k)
          wbuf[k] = *(const float4*)(Wsol + ((long)(b * NB + blk + 1) << 10) +
                                     tid * 32 + (k << 2));
        pcur = pb[(blk + 1) * 32 + tid];
      }
    }
    __syncthreads();
  }
}

// ---------------------------------------------------------------------------
// m partials, float4-vectorized: chunk c covers 16 t; wave w handles
// t = t0 + {w, w+4, w+8, w+12}; lane loads dwordx4 of the h row.
// 256 blocks — full-occupancy version (grid-8 fusion was latency-bound: 46 us).
// ---------------------------------------------------------------------------
__global__ __launch_bounds__(256) void k_mrp(
    const float* __restrict__ h, const float* __restrict__ d_all,
    float* __restrict__ part)
{
  __shared__ float acc_s[4][Hz];
  const int c = blockIdx.x, b = blockIdx.y, tid = threadIdx.x;
  const int w = tid >> 6, lane = tid & 63;
  const float* hb = h + (long)b * Lz * Hz;
  const float* db = d_all + ((long)b << 9);
  const int t0 = c * 16;
  const int off = lane << 2;
  float4 acc = {0.f, 0.f, 0.f, 0.f};
#pragma unroll
  for (int q = 0; q < 4; ++q) {
    const int t = t0 + (q << 2) + w;
    if (t < 511) {
      const float dv = db[510 - t];
      const float4 hv = *(const float4*)(hb + (long)t * Hz + off);
      acc.x = fmaf(dv, hv.x, acc.x); acc.y = fmaf(dv, hv.y, acc.y);
      acc.z = fmaf(dv, hv.z, acc.z); acc.w = fmaf(dv, hv.w, acc.w);
    }
  }
  *(float4*)&acc_s[w][off] = acc;
  __syncthreads();
  if (tid < Hz) {
    part[((long)b * 32 + c) * Hz + tid] =
        acc_s[0][tid] + acc_s[1][tid] + acc_s[2][tid] + acc_s[3][tid];
  }
}

// ---------------------------------------------------------------------------
// Combine partials -> m; r = m @ Wrp + brp.  8 WGs.
// ---------------------------------------------------------------------------
__global__ __launch_bounds__(256) void k_mr2(
    const float* __restrict__ part, const float* __restrict__ Wrp,
    const float* __restrict__ brp, float* __restrict__ r)
{
  __shared__ float ms[Hz];
  const int b = blockIdx.x, tid = threadIdx.x;
  float acc = 0.0f;
#pragma unroll
  for (int c = 0; c < 32; ++c) acc += part[((long)b * 32 + c) * Hz + tid];
  ms[tid] = CF * acc;
  __syncthreads();
  float racc = 0.0f;
#pragma unroll 8
  for (int e = 0; e < Hz; ++e)
    racc = fmaf(ms[e], Wrp[(long)e * Hz + tid], racc);
  r[b * Hz + tid] = racc + brp[tid];
}

// ---------------------------------------------------------------------------
// out[8,32000] = r[8,256] @ Wout[256,32000] + bout.
// ---------------------------------------------------------------------------
__global__ __launch_bounds__(256) void k_outproj(
    const float* __restrict__ r, const float* __restrict__ Wout,
    const float* __restrict__ bout, float* __restrict__ out)
{
  __shared__ float rs[8 * Hz];
  __shared__ float part[4][8][64];
  const int tid = threadIdx.x, w = tid >> 6, lane = tid & 63;
  ((float4*)rs)[tid * 2 + 0] = ((const float4*)r)[tid * 2 + 0];
  ((float4*)rs)[tid * 2 + 1] = ((const float4*)r)[tid * 2 + 1];
  __syncthreads();
  const int col = blockIdx.x * 64 + lane;
  float acc[8] = {};
  const int i0 = w << 6;
#pragma unroll 8
  for (int ii = 0; ii < 64; ++ii) {
    const int i = i0 + ii;
    const float wv = Wout[(long)i * Vz + col];
#pragma unroll
    for (int bb = 0; bb < 8; ++bb) acc[bb] = fmaf(rs[bb * Hz + i], wv, acc[bb]);
  }
#pragma unroll
  for (int bb = 0; bb < 8; ++bb) part[w][bb][lane] = acc[bb];
  __syncthreads();
  const float bo = bout[col];
  float s0 = part[0][w][lane] + part[1][w][lane] + part[2][w][lane] + part[3][w][lane];
  out[(long)w * Vz + col] = s0 + bo;
  const int w4 = w + 4;
  float s1 = part[0][w4][lane] + part[1][w4][lane] + part[2][w4][lane] + part[3][w4][lane];
  out[(long)w4 * Vz + col] = s1 + bo;
}

// ---------------------------------------------------------------------------
extern "C" void kernel_launch(void* const* d_in, const int* in_sizes, int n_in,
                              void* d_out, int out_size, void* d_ws, size_t ws_size,
                              hipStream_t stream)
{
  const int*   seq   = (const int*)  d_in[0];
  const float* embed = (const float*)d_in[1];
  const float* W1    = (const float*)d_in[2];
  const float* b1    = (const float*)d_in[3];
  const float* W2    = (const float*)d_in[4];
  const float* b2    = (const float*)d_in[5];
  const float* gamma = (const float*)d_in[6];
  const float* beta  = (const float*)d_in[7];
  const float* Wrp   = (const float*)d_in[8];
  const float* brp   = (const float*)d_in[9];
  const float* Wout  = (const float*)d_in[10];
  const float* bout  = (const float*)d_in[11];
  float* out = (float*)d_out;

  char* ws = (char*)d_ws;
  const size_t MB = 1024u * 1024u;
  // Temporal overlay: y1bf dies after k_mfma2ln; Gf written by k_gramT (later).
  short* y1bf = (short*)(ws);                        // 4 MB  [0,4)
  float* Gf   = (float*)(ws);                        // 8 MB  [0,8)  (after mfma2ln)
  float* hb   = (float*)(ws + 8 * MB);               // 4 MB
  float* hnb  = (float*)(ws + 12 * MB);              // 4 MB
  short* Knb  = (short*)(ws + 16 * MB);              // 2 MB  bf16 s-order keys
  short* Wt1  = (short*)(ws + 18 * MB);              // 256 KB
  short* Wt2  = (short*)(ws + 18 * MB + 256 * 1024); // 256 KB
  float* Wsol = (float*)(ws + 18 * MB + 512 * 1024); // 512 KB
  float* pbuf = (float*)(ws + 19 * MB);                        // 16 KB
  float* dall = (float*)(ws + 19 * MB + 16 * 1024);            // 16 KB
  float* prt  = (float*)(ws + 19 * MB + 32 * 1024);            // 256 KB
  float* rb   = (float*)(ws + 19 * MB + 288 * 1024);           // 8 KB
  short* Eg   = (short*)(ws + 20 * MB);              // 2 MB bf16 gathered embed

  k_wcvt2<<<320, 256, 0, stream>>>(W1, W2, seq, embed, Wt1, Wt2, Eg);
  k_mfma1<<<dim3(H2z / 64, Mz / 64), 256, 0, stream>>>(Eg, Wt1, b1, y1bf);
  k_mfma2ln<<<Mz / 16, 256, 0, stream>>>(seq, embed, y1bf, Wt2, b2, gamma, beta,
                                         hb, hnb, Knb);
  k_gramT<<<dim3(8, 8, Bz), 256, 0, stream>>>(Knb, hb, hnb, Gf, Wsol, pbuf);
  k_solve<<<Bz, 256, 0, stream>>>(Gf, pbuf, Wsol, dall);
  k_mrp<<<dim3(32, Bz), 256, 0, stream>>>(hb, dall, prt);
  k_mr2<<<Bz, 256, 0, stream>>>(prt, Wrp, brp, rb);
  k_outproj<<<Vz / 64, 256, 0, stream>>>(rb, Wout, bout, out);
}

// Round 5
// 167.674 us; speedup vs baseline: 1.3441x; 1.0591x over previous
//
#include <hip/hip_runtime.h>

// Problem constants
constexpr int Bz  = 8;
constexpr int Lz  = 512;
constexpr int Hz  = 256;
constexpr int H2z = 512;
constexpr int Vz  = 32000;
constexpr int Mz  = Bz * Lz;      // 4096 tokens
constexpr float CF = 0.05f;       // 1 - ALPHA
constexpr int NB  = 16;           // 16 blocks of 32 = 512 (511 real + 1 dummy)

typedef __attribute__((ext_vector_type(8))) short bfrag8;   // 8 bf16
typedef __attribute__((ext_vector_type(4))) float f32x4v;
typedef __attribute__((ext_vector_type(4))) short s4v;

static __device__ __forceinline__ short f2bf(float f) {
  unsigned u = __builtin_bit_cast(unsigned, f);
  u += 0x7fffu + ((u >> 16) & 1u);           // round-to-nearest-even
  return (short)(u >> 16);
}

// ---------------------------------------------------------------------------
// Weight transpose+convert + embedding gather->bf16, one launch.
// blocks [0,32): W1 tiles; [32,64): W2 tiles; [64,320): Eg gather.
// ---------------------------------------------------------------------------
static __device__ __forceinline__ void wcvt_tile(
    const float* __restrict__ src, short* __restrict__ dst,
    int K, int N, int n0, int k0, int tid)
{
  __shared__ float tile[64][68];
  const int rr = tid >> 4, c4 = (tid & 15) << 2;
#pragma unroll
  for (int q = 0; q < 4; ++q) {
    const int kr = rr + q * 16;
    *(float4*)&tile[kr][c4] = *(const float4*)(src + (long)(k0 + kr) * N + n0 + c4);
  }
  __syncthreads();
#pragma unroll
  for (int q = 0; q < 4; ++q) {
    const int nr = rr + q * 16;
    s4v o = { f2bf(tile[c4 + 0][nr]), f2bf(tile[c4 + 1][nr]),
              f2bf(tile[c4 + 2][nr]), f2bf(tile[c4 + 3][nr]) };
    *(s4v*)(dst + (long)(n0 + nr) * K + k0 + c4) = o;
  }
}

__global__ __launch_bounds__(256) void k_wcvt2(
    const float* __restrict__ W1, const float* __restrict__ W2,
    const int* __restrict__ seq, const float* __restrict__ embed,
    short* __restrict__ Wt1, short* __restrict__ Wt2, short* __restrict__ Eg)
{
  const int bx = blockIdx.x, tid = threadIdx.x;
  if (bx < 32) {
    wcvt_tile(W1, Wt1, Hz, H2z, (bx & 7) * 64, (bx >> 3) * 64, tid);
  } else if (bx < 64) {
    const int b2 = bx - 32;
    wcvt_tile(W2, Wt2, H2z, Hz, (b2 & 3) * 64, (b2 >> 2) * 64, tid);
  } else {
    // Eg[row][:] = bf16(embed[seq[row]][:]), 16 rows per block
    const int row = (bx - 64) * 16 + (tid >> 4);
    const int c0 = (tid & 15) << 4;
    const long src = (long)seq[row] * Hz + c0;
    const float4 v0 = *(const float4*)(embed + src);
    const float4 v1 = *(const float4*)(embed + src + 4);
    const float4 v2 = *(const float4*)(embed + src + 8);
    const float4 v3 = *(const float4*)(embed + src + 12);
    bfrag8 o0 = { f2bf(v0.x), f2bf(v0.y), f2bf(v0.z), f2bf(v0.w),
                  f2bf(v1.x), f2bf(v1.y), f2bf(v1.z), f2bf(v1.w) };
    bfrag8 o1 = { f2bf(v2.x), f2bf(v2.y), f2bf(v2.z), f2bf(v2.w),
                  f2bf(v3.x), f2bf(v3.y), f2bf(v3.z), f2bf(v3.w) };
    *(bfrag8*)(Eg + (long)row * Hz + c0) = o0;
    *(bfrag8*)(Eg + (long)row * Hz + c0 + 8) = o1;
  }
}

// ---------------------------------------------------------------------------
// MFMA GEMM1: y1bf[4096,512] = bf16(relu(Eg @ Wt1^T + b1)); Eg pre-gathered bf16.
// ---------------------------------------------------------------------------
__global__ __launch_bounds__(256) void k_mfma1(
    const short* __restrict__ Eg, const short* __restrict__ Wt1,
    const float* __restrict__ b1, short* __restrict__ y1bf)
{
  __shared__ short As[64][32];
  __shared__ short Bs[64][32];
  const int tid = threadIdx.x;
  const int n0 = blockIdx.x * 64, m0 = blockIdx.y * 64;
  const int w = tid >> 6, l = tid & 63;
  const int srow = tid >> 2, skq = (tid & 3) << 3;
  const f32x4v zero = {0.f, 0.f, 0.f, 0.f};
  f32x4v acc[4] = {zero, zero, zero, zero};
  for (int kc = 0; kc < Hz; kc += 32) {
    const bfrag8 avl = *(const bfrag8*)(Eg + (long)(m0 + srow) * Hz + kc + skq);
    const bfrag8 bvl = *(const bfrag8*)(Wt1 + (long)(n0 + srow) * Hz + kc + skq);
    __syncthreads();
    *(bfrag8*)&As[srow][skq] = avl;
    *(bfrag8*)&Bs[srow][skq] = bvl;
    __syncthreads();
    const bfrag8 a = *(const bfrag8*)&As[(w << 4) + (l & 15)][(l >> 4) << 3];
#pragma unroll
    for (int nn = 0; nn < 4; ++nn) {
      const bfrag8 bb = *(const bfrag8*)&Bs[(nn << 4) + (l & 15)][(l >> 4) << 3];
      acc[nn] = __builtin_amdgcn_mfma_f32_16x16x32_bf16(a, bb, acc[nn], 0, 0, 0);
    }
  }
  const int col0 = l & 15, quad = l >> 4;
#pragma unroll
  for (int nn = 0; nn < 4; ++nn) {
    const int col = n0 + (nn << 4) + col0;
    const float bias = b1[col];
#pragma unroll
    for (int i = 0; i < 4; ++i) {
      const int row = m0 + (w << 4) + (quad << 2) + i;
      y1bf[(long)row * H2z + col] = f2bf(fmaxf(acc[nn][i] + bias, 0.0f));
    }
  }
}

// ---------------------------------------------------------------------------
// FUSED GEMM2 + residual + LayerNorm + L2-normalize, full-occupancy version.
// Grid: 256 blocks x 16 rows. 4 waves split the 256 cols (64 each, 4 frags).
// ---------------------------------------------------------------------------
__global__ __launch_bounds__(256) void k_mfma2ln(
    const int* __restrict__ seq, const float* __restrict__ embed,
    const short* __restrict__ y1bf, const short* __restrict__ Wt2,
    const float* __restrict__ b2, const float* __restrict__ gamma,
    const float* __restrict__ beta, float* __restrict__ h,
    float* __restrict__ hn, short* __restrict__ Knb)
{
  __shared__ short As[16][32];     // 1 KB
  __shared__ short Bs[256][32];    // 16 KB (all 256 output cols of Wt2)
  __shared__ float red[4][16][2];  // per-wave LN partials (s, ss)
  __shared__ float red2[4][16];    // per-wave L2 partials
  const int tid = threadIdx.x;
  const int m0 = blockIdx.x * 16;
  const int w = tid >> 6, l = tid & 63;
  const int srow = tid >> 2, skq = (tid & 3) << 3;
  const f32x4v zero = {0.f, 0.f, 0.f, 0.f};
  f32x4v acc[4] = {zero, zero, zero, zero};

  for (int kc = 0; kc < H2z; kc += 32) {
    bfrag8 av = {};
    if (tid < 64)
      av = *(const bfrag8*)(y1bf + (long)(m0 + (tid >> 2)) * H2z + kc + skq);
    bfrag8 bv[4];
#pragma unroll
    for (int q = 0; q < 4; ++q)
      bv[q] = *(const bfrag8*)(Wt2 + (long)(srow + (q << 6)) * H2z + kc + skq);
    __syncthreads();
    if (tid < 64) *(bfrag8*)&As[tid >> 2][skq] = av;
#pragma unroll
    for (int q = 0; q < 4; ++q)
      *(bfrag8*)&Bs[srow + (q << 6)][skq] = bv[q];
    __syncthreads();
    const bfrag8 a = *(const bfrag8*)&As[l & 15][(l >> 4) << 3];
#pragma unroll
    for (int nn = 0; nn < 4; ++nn) {
      const bfrag8 bb = *(const bfrag8*)&Bs[(w << 6) + (nn << 4) + (l & 15)][(l >> 4) << 3];
      acc[nn] = __builtin_amdgcn_mfma_f32_16x16x32_bf16(a, bb, acc[nn], 0, 0, 0);
    }
  }

  const int col0 = l & 15, quad = l >> 4;
  float g_r[4], be_r[4], b2_r[4];
#pragma unroll
  for (int nn = 0; nn < 4; ++nn) {
    const int col = (w << 6) + (nn << 4) + col0;
    g_r[nn] = gamma[col]; be_r[nn] = beta[col]; b2_r[nn] = b2[col];
  }

  // pass 1: residual add, per-row mean/var partials (this wave's 64 cols)
  float v[4][4];                    // [i][nn]
#pragma unroll
  for (int i = 0; i < 4; ++i) {
    const int lr = (quad << 2) + i;
    const int row = m0 + lr;
    const long ebase = (long)seq[row] * Hz;
    float s = 0.0f, ss = 0.0f;
#pragma unroll
    for (int nn = 0; nn < 4; ++nn) {
      const int col = (w << 6) + (nn << 4) + col0;
      const float t = acc[nn][i] + b2_r[nn] + embed[ebase + col];
      v[i][nn] = t; s += t; ss += t * t;
    }
#pragma unroll
    for (int o = 8; o >= 1; o >>= 1) { s += __shfl_xor(s, o); ss += __shfl_xor(ss, o); }
    if ((l & 15) == 0) { red[w][lr][0] = s; red[w][lr][1] = ss; }
  }
  __syncthreads();

  // pass 2: LN normalize, per-row L2 partials
#pragma unroll
  for (int i = 0; i < 4; ++i) {
    const int lr = (quad << 2) + i;
    const float s  = red[0][lr][0] + red[1][lr][0] + red[2][lr][0] + red[3][lr][0];
    const float ss = red[0][lr][1] + red[1][lr][1] + red[2][lr][1] + red[3][lr][1];
    const float mu   = s * (1.0f / Hz);
    const float var  = ss * (1.0f / Hz) - mu * mu;
    const float rstd = rsqrtf(var + 1e-5f);
    float hs = 0.0f;
#pragma unroll
    for (int nn = 0; nn < 4; ++nn) {
      const float hv = (v[i][nn] - mu) * rstd * g_r[nn] + be_r[nn];
      v[i][nn] = hv; hs += hv * hv;
    }
#pragma unroll
    for (int o = 8; o >= 1; o >>= 1) hs += __shfl_xor(hs, o);
    if ((l & 15) == 0) red2[w][lr] = hs;
  }
  __syncthreads();

  // pass 3: L2 normalize + stores
#pragma unroll
  for (int i = 0; i < 4; ++i) {
    const int lr = (quad << 2) + i;
    const float hs = red2[0][lr] + red2[1][lr] + red2[2][lr] + red2[3][lr];
    const float inv = 1.0f / fmaxf(sqrtf(hs), 1e-12f);
    const int row = m0 + lr;
    float* hrow  = h  + (long)row * Hz;
    float* hnrow = hn + (long)row * Hz;
    const int bb_ = row >> 9, t = row & 511;
    short* kr = Knb + ((long)bb_ * 512 + (t < 511 ? 510 - t : 511)) * Hz;
#pragma unroll
    for (int nn = 0; nn < 4; ++nn) {
      const int col = (w << 6) + (nn << 4) + col0;
      const float hv = v[i][nn];
      const float nv = hv * inv;
      hrow[col]  = hv;
      hnrow[col] = nv;
      kr[col] = (t < 511) ? f2bf(nv) : (short)0;
    }
  }
}

// ---------------------------------------------------------------------------
// Full Gram via bf16 MFMA (lower tiles), with FUSED block-diag inverse
// (one wave per 32x32 diag block) AND fused p computation on idle upper blocks.
// ---------------------------------------------------------------------------
__global__ __launch_bounds__(256) void k_gramT(
    const short* __restrict__ Knb, const float* __restrict__ h,
    const float* __restrict__ hn, float* __restrict__ G,
    float* __restrict__ Wsol, float* __restrict__ p)
{
  const int nb = blockIdx.x, mb = blockIdx.y, b = blockIdx.z;
  __shared__ short As[64][32];
  __shared__ short Bs[64][32];
  __shared__ float Gs2[2][32][33];
  __shared__ float qs[Hz];
  if (nb > mb) {
    // repurposed idle block: p chunk (block-uniform branch, syncthreads legal)
    const int idx = ((nb * (nb - 1)) >> 1) + mb;   // 0..27 upper-tri enumeration
    if (idx >= 16) return;
    const int tid = threadIdx.x;
    qs[tid] = h[((long)b * Lz + 511) * Hz + tid];
    __syncthreads();
    const int s = idx * 32 + (tid >> 3);           // 32 s-rows per block
    const int g = tid & 7;                         // 8 threads per row, 32 ch each
    float acc = 0.0f;
    if (s <= 510) {
      const float* src = hn + ((long)b * Lz + (510 - s)) * Hz + (g << 5);
#pragma unroll
      for (int q = 0; q < 8; ++q) {
        const float4 vv = *(const float4*)(src + 4 * q);
        const int c = (g << 5) + 4 * q;
        acc += vv.x * qs[c] + vv.y * qs[c + 1] + vv.z * qs[c + 2] + vv.w * qs[c + 3];
      }
    }
#pragma unroll
    for (int o = 4; o >= 1; o >>= 1) acc += __shfl_xor(acc, o);
    if (g == 0) p[(long)b * 512 + s] = acc;        // s==511 writes 0 (dummy)
    return;
  }
  const short* Kb = Knb + (long)b * 512 * Hz;
  const int tid = threadIdx.x;
  const int w = tid >> 6, l = tid & 63;
  const int srow = tid >> 2, skq = (tid & 3) << 3;
  const f32x4v zero = {0.f, 0.f, 0.f, 0.f};
  f32x4v acc[4] = {zero, zero, zero, zero};
  for (int kc = 0; kc < Hz; kc += 32) {
    __syncthreads();
    *(bfrag8*)&As[srow][skq] = *(const bfrag8*)(Kb + (long)(mb * 64 + srow) * Hz + kc + skq);
    *(bfrag8*)&Bs[srow][skq] = *(const bfrag8*)(Kb + (long)(nb * 64 + srow) * Hz + kc + skq);
    __syncthreads();
    const bfrag8 a = *(const bfrag8*)&As[(w << 4) + (l & 15)][(l >> 4) << 3];
#pragma unroll
    for (int nn = 0; nn < 4; ++nn) {
      const bfrag8 bb = *(const bfrag8*)&Bs[(nn << 4) + (l & 15)][(l >> 4) << 3];
      acc[nn] = __builtin_amdgcn_mfma_f32_16x16x32_bf16(a, bb, acc[nn], 0, 0, 0);
    }
  }
  const int col0 = l & 15, quad = l >> 4;
  float* Gb = G + (long)b * 512 * 512;
#pragma unroll
  for (int nn = 0; nn < 4; ++nn) {
    const int col = nb * 64 + (nn << 4) + col0;
#pragma unroll
    for (int i = 0; i < 4; ++i) {
      const int row = mb * 64 + (w << 4) + (quad << 2) + i;
      Gb[(long)row * 512 + col] = acc[nn][i];
    }
  }
  if (mb != nb) return;
#pragma unroll
  for (int nn = 0; nn < 4; ++nn) {
    const int lc = (nn << 4) + col0;
#pragma unroll
    for (int i = 0; i < 4; ++i) {
      const int lr = (w << 4) + (quad << 2) + i;
      if ((lr >> 5) == (lc >> 5)) Gs2[lr >> 5][lr & 31][lc & 31] = acc[nn][i];
    }
  }
  __syncthreads();
  if (w < 2 && l < 32) {       // wave w inverts sub-block w; lane = column c
    const int c = l;
    float wv[32];
    wv[0] = (c == 0) ? 1.0f : 0.0f;
#pragma unroll
    for (int i = 1; i < 32; ++i) {
      float sum = 0.0f;
#pragma unroll
      for (int j = 0; j < i; ++j) sum = fmaf(Gs2[w][i][j], wv[j], sum);
      wv[i] = ((i == c) ? 1.0f : 0.0f) - CF * sum;
    }
    const int blk = mb * 2 + w;
    float* dst = Wsol + ((long)(b * NB + blk) << 10) + c;
#pragma unroll
    for (int i = 0; i < 32; ++i) dst[i * 32] = wv[i];
  }
}

// ---------------------------------------------------------------------------
// Block-triangular solve with REGISTER PREFETCH + split diag matvec:
// wave0's 64 lanes pair up (row = tid&31, half = tid>>5) so the 32-deep
// dependent Wsol.rhs fma chain becomes 16-deep + one __shfl_xor combine.
// ---------------------------------------------------------------------------
__global__ __launch_bounds__(256) void k_solve(
    const float* __restrict__ G, const float* __restrict__ p,
    const float* __restrict__ Wsol, float* __restrict__ d_all)
{
  __shared__ float ds[512];
  __shared__ float part[32][9];
  __shared__ float rhs[32];
  const int b = blockIdx.x, tid = threadIdx.x;
  const int i = tid >> 3, g = tid & 7;
  const float* Gb = G + (long)b * 512 * 512;
  const float* pb = p + (long)b * 512;

  float4 gbuf[15];                 // G[blk*32+i][bp*32+g*4] for current step
  float4 wbuf[4];                  // wave0: half a Wsol row (16 elems)
  float  pcur = 0.0f;
  const int row = tid & 31, half = (tid >> 5) & 1;
  if (tid < 64) {
#pragma unroll
    for (int k = 0; k < 4; ++k)
      wbuf[k] = *(const float4*)(Wsol + ((long)(b * NB) << 10) +
                                 row * 32 + half * 16 + (k << 2));
    if (tid < 32) pcur = pb[tid];
  }

  for (int blk = 0; blk < NB; ++blk) {
    // off-diagonal matvec using prefetched gbuf (empty at blk=0)
    float acc = 0.0f;
#pragma unroll
    for (int bp = 0; bp < 15; ++bp) {
      if (bp < blk) {
        const int j = bp * 32 + (g << 2);
        acc += gbuf[bp].x * ds[j]     + gbuf[bp].y * ds[j + 1] +
               gbuf[bp].z * ds[j + 2] + gbuf[bp].w * ds[j + 3];
      }
    }
    part[i][g] = acc;
    // issue G prefetch for step blk+1 (independent of ds; hides under barriers)
    if (blk + 1 < NB) {
      const float* grow = Gb + (long)((blk + 1) * 32 + i) * 512 + (g << 2);
#pragma unroll
      for (int bp = 0; bp < 15; ++bp)
        if (bp <= blk) gbuf[bp] = *(const float4*)(grow + bp * 32);
    }
    __syncthreads();
    if (tid < 64) {               // wave 0 only, wave-synchronous from here
      if (tid < 32) {
        const float c = part[tid][0] + part[tid][1] + part[tid][2] + part[tid][3] +
                        part[tid][4] + part[tid][5] + part[tid][6] + part[tid][7];
        rhs[tid] = pcur - CF * c;
      }
      // rhs written by lanes 0-31, read by all 64 lanes of this wave (lockstep)
      float dvh = 0.0f;
#pragma unroll
      for (int k = 0; k < 4; ++k) {
        const int k0 = half * 16 + (k << 2);
        dvh += wbuf[k].x * rhs[k0]     + wbuf[k].y * rhs[k0 + 1] +
               wbuf[k].z * rhs[k0 + 2] + wbuf[k].w * rhs[k0 + 3];
      }
      float dv = dvh + __shfl_xor(dvh, 32);
      if (tid < 32) {
        if (blk == NB - 1 && tid == 31) dv = 0.0f;   // dummy s=511
        ds[blk * 32 + tid] = dv;
        d_all[(long)b * 512 + blk * 32 + tid] = dv;
        if (blk + 1 < NB) pcur = pb[(blk + 1) * 32 + tid];
      }
      // prefetch Wsol for step blk+1
      if (blk + 1 < NB) {
#pragma unroll
        for (int k = 0; k < 4; ++k)
          wbuf[k] = *(const float4*)(Wsol + ((long)(b * NB + blk + 1) << 10) +
                                     row * 32 + half * 16 + (k << 2));
      }
    }
    __syncthreads();
  }
}

// ---------------------------------------------------------------------------
// m partials, float4-vectorized: chunk c covers 16 t; wave w handles
// t = t0 + {w, w+4, w+8, w+12}; lane loads dwordx4 of the h row.
// 256 blocks — full-occupancy version (grid-8 fusion was latency-bound: 46 us).
// ---------------------------------------------------------------------------
__global__ __launch_bounds__(256) void k_mrp(
    const float* __restrict__ h, const float* __restrict__ d_all,
    float* __restrict__ part)
{
  __shared__ float acc_s[4][Hz];
  const int c = blockIdx.x, b = blockIdx.y, tid = threadIdx.x;
  const int w = tid >> 6, lane = tid & 63;
  const float* hb = h + (long)b * Lz * Hz;
  const float* db = d_all + ((long)b << 9);
  const int t0 = c * 16;
  const int off = lane << 2;
  float4 acc = {0.f, 0.f, 0.f, 0.f};
#pragma unroll
  for (int q = 0; q < 4; ++q) {
    const int t = t0 + (q << 2) + w;
    if (t < 511) {
      const float dv = db[510 - t];
      const float4 hv = *(const float4*)(hb + (long)t * Hz + off);
      acc.x = fmaf(dv, hv.x, acc.x); acc.y = fmaf(dv, hv.y, acc.y);
      acc.z = fmaf(dv, hv.z, acc.z); acc.w = fmaf(dv, hv.w, acc.w);
    }
  }
  *(float4*)&acc_s[w][off] = acc;
  __syncthreads();
  if (tid < Hz) {
    part[((long)b * 32 + c) * Hz + tid] =
        acc_s[0][tid] + acc_s[1][tid] + acc_s[2][tid] + acc_s[3][tid];
  }
}

// ---------------------------------------------------------------------------
// Combine partials -> m; r = m @ Wrp + brp.  Parallel version: grid (4, Bz),
// 64 cols per block, 4 e-groups of 64 per thread-col, coalesced Wrp reads,
// 4-way LDS reduce. (8-WG version was latency-bound: strided serial loads.)
// ---------------------------------------------------------------------------
__global__ __launch_bounds__(256) void k_mr2(
    const float* __restrict__ part, const float* __restrict__ Wrp,
    const float* __restrict__ brp, float* __restrict__ r)
{
  __shared__ float ms[Hz];
  __shared__ float red[4][64];
  const int c4 = blockIdx.x, b = blockIdx.y, tid = threadIdx.x;
  const int lane = tid & 63, eg = tid >> 6;
  float a = 0.0f;
#pragma unroll
  for (int c = 0; c < 32; ++c) a += part[((long)b * 32 + c) * Hz + tid];
  ms[tid] = CF * a;
  __syncthreads();
  const int col = (c4 << 6) + lane;
  float racc = 0.0f;
#pragma unroll 16
  for (int k = 0; k < 64; ++k) {
    const int e = (eg << 6) + k;
    racc = fmaf(ms[e], Wrp[(long)e * Hz + col], racc);
  }
  red[eg][lane] = racc;
  __syncthreads();
  if (tid < 64)
    r[b * Hz + (c4 << 6) + tid] =
        red[0][tid] + red[1][tid] + red[2][tid] + red[3][tid] + brp[(c4 << 6) + tid];
}

// ---------------------------------------------------------------------------
// out[8,32000] = r[8,256] @ Wout[256,32000] + bout.
// ---------------------------------------------------------------------------
__global__ __launch_bounds__(256) void k_outproj(
    const float* __restrict__ r, const float* __restrict__ Wout,
    const float* __restrict__ bout, float* __restrict__ out)
{
  __shared__ float rs[8 * Hz];
  __shared__ float part[4][8][64];
  const int tid = threadIdx.x, w = tid >> 6, lane = tid & 63;
  ((float4*)rs)[tid * 2 + 0] = ((const float4*)r)[tid * 2 + 0];
  ((float4*)rs)[tid * 2 + 1] = ((const float4*)r)[tid * 2 + 1];
  __syncthreads();
  const int col = blockIdx.x * 64 + lane;
  float acc[8] = {};
  const int i0 = w << 6;
#pragma unroll 8
  for (int ii = 0; ii < 64; ++ii) {
    const int i = i0 + ii;
    const float wv = Wout[(long)i * Vz + col];
#pragma unroll
    for (int bb = 0; bb < 8; ++bb) acc[bb] = fmaf(rs[bb * Hz + i], wv, acc[bb]);
  }
#pragma unroll
  for (int bb = 0; bb < 8; ++bb) part[w][bb][lane] = acc[bb];
  __syncthreads();
  const float bo = bout[col];
  float s0 = part[0][w][lane] + part[1][w][lane] + part[2][w][lane] + part[3][w][lane];
  out[(long)w * Vz + col] = s0 + bo;
  const int w4 = w + 4;
  float s1 = part[0][w4][lane] + part[1][w4][lane] + part[2][w4][lane] + part[3][w4][lane];
  out[(long)w4 * Vz + col] = s1 + bo;
}

// ---------------------------------------------------------------------------
extern "C" void kernel_launch(void* const* d_in, const int* in_sizes, int n_in,
                              void* d_out, int out_size, void* d_ws, size_t ws_size,
                              hipStream_t stream)
{
  const int*   seq   = (const int*)  d_in[0];
  const float* embed = (const float*)d_in[1];
  const float* W1    = (const float*)d_in[2];
  const float* b1    = (const float*)d_in[3];
  const float* W2    = (const float*)d_in[4];
  const float* b2    = (const float*)d_in[5];
  const float* gamma = (const float*)d_in[6];
  const float* beta  = (const float*)d_in[7];
  const float* Wrp   = (const float*)d_in[8];
  const float* brp   = (const float*)d_in[9];
  const float* Wout  = (const float*)d_in[10];
  const float* bout  = (const float*)d_in[11];
  float* out = (float*)d_out;

  char* ws = (char*)d_ws;
  const size_t MB = 1024u * 1024u;
  // Temporal overlay: y1bf dies after k_mfma2ln; Gf written by k_gramT (later).
  short* y1bf = (short*)(ws);                        // 4 MB  [0,4)
  float* Gf   = (float*)(ws);                        // 8 MB  [0,8)  (after mfma2ln)
  float* hb   = (float*)(ws + 8 * MB);               // 4 MB
  float* hnb  = (float*)(ws + 12 * MB);              // 4 MB
  short* Knb  = (short*)(ws + 16 * MB);              // 2 MB  bf16 s-order keys
  short* Wt1  = (short*)(ws + 18 * MB);              // 256 KB
  short* Wt2  = (short*)(ws + 18 * MB + 256 * 1024); // 256 KB
  float* Wsol = (float*)(ws + 18 * MB + 512 * 1024); // 512 KB
  float* pbuf = (float*)(ws + 19 * MB);                        // 16 KB
  float* dall = (float*)(ws + 19 * MB + 16 * 1024);            // 16 KB
  float* prt  = (float*)(ws + 19 * MB + 32 * 1024);            // 256 KB
  float* rb   = (float*)(ws + 19 * MB + 288 * 1024);           // 8 KB
  short* Eg   = (short*)(ws + 20 * MB);              // 2 MB bf16 gathered embed

  k_wcvt2<<<320, 256, 0, stream>>>(W1, W2, seq, embed, Wt1, Wt2, Eg);
  k_mfma1<<<dim3(H2z / 64, Mz / 64), 256, 0, stream>>>(Eg, Wt1, b1, y1bf);
  k_mfma2ln<<<Mz / 16, 256, 0, stream>>>(seq, embed, y1bf, Wt2, b2, gamma, beta,
                                         hb, hnb, Knb);
  k_gramT<<<dim3(8, 8, Bz), 256, 0, stream>>>(Knb, hb, hnb, Gf, Wsol, pbuf);
  k_solve<<<Bz, 256, 0, stream>>>(Gf, pbuf, Wsol, dall);
  k_mrp<<<dim3(32, Bz), 256, 0, stream>>>(hb, dall, prt);
  k_mr2<<<dim3(4, Bz), 256, 0, stream>>>(prt, Wrp, brp, rb);
  k_outproj<<<Vz / 64, 256, 0, stream>>>(rb, Wout, bout, out);
}

// Round 6
// 165.823 us; speedup vs baseline: 1.3591x; 1.0112x over previous
//
#include <hip/hip_runtime.h>

// Problem constants
constexpr int Bz  = 8;
constexpr int Lz  = 512;
constexpr int Hz  = 256;
constexpr int H2z = 512;
constexpr int Vz  = 32000;
constexpr int Mz  = Bz * Lz;      // 4096 tokens
constexpr float CF = 0.05f;       // 1 - ALPHA
constexpr int NB  = 16;           // 16 blocks of 32 = 512 (511 real + 1 dummy)

typedef __attribute__((ext_vector_type(8))) short bfrag8;   // 8 bf16
typedef __attribute__((ext_vector_type(4))) float f32x4v;
typedef __attribute__((ext_vector_type(4))) short s4v;

static __device__ __forceinline__ short f2bf(float f) {
  unsigned u = __builtin_bit_cast(unsigned, f);
  u += 0x7fffu + ((u >> 16) & 1u);           // round-to-nearest-even
  return (short)(u >> 16);
}

// ---------------------------------------------------------------------------
// Weight transpose+convert + embedding gather->bf16, one launch.
// blocks [0,32): W1 tiles; [32,64): W2 tiles; [64,320): Eg gather.
// ---------------------------------------------------------------------------
static __device__ __forceinline__ void wcvt_tile(
    const float* __restrict__ src, short* __restrict__ dst,
    int K, int N, int n0, int k0, int tid)
{
  __shared__ float tile[64][68];
  const int rr = tid >> 4, c4 = (tid & 15) << 2;
#pragma unroll
  for (int q = 0; q < 4; ++q) {
    const int kr = rr + q * 16;
    *(float4*)&tile[kr][c4] = *(const float4*)(src + (long)(k0 + kr) * N + n0 + c4);
  }
  __syncthreads();
#pragma unroll
  for (int q = 0; q < 4; ++q) {
    const int nr = rr + q * 16;
    s4v o = { f2bf(tile[c4 + 0][nr]), f2bf(tile[c4 + 1][nr]),
              f2bf(tile[c4 + 2][nr]), f2bf(tile[c4 + 3][nr]) };
    *(s4v*)(dst + (long)(n0 + nr) * K + k0 + c4) = o;
  }
}

__global__ __launch_bounds__(256) void k_wcvt2(
    const float* __restrict__ W1, const float* __restrict__ W2,
    const int* __restrict__ seq, const float* __restrict__ embed,
    short* __restrict__ Wt1, short* __restrict__ Wt2, short* __restrict__ Eg)
{
  const int bx = blockIdx.x, tid = threadIdx.x;
  if (bx < 32) {
    wcvt_tile(W1, Wt1, Hz, H2z, (bx & 7) * 64, (bx >> 3) * 64, tid);
  } else if (bx < 64) {
    const int b2 = bx - 32;
    wcvt_tile(W2, Wt2, H2z, Hz, (b2 & 3) * 64, (b2 >> 2) * 64, tid);
  } else {
    // Eg[row][:] = bf16(embed[seq[row]][:]), 16 rows per block
    const int row = (bx - 64) * 16 + (tid >> 4);
    const int c0 = (tid & 15) << 4;
    const long src = (long)seq[row] * Hz + c0;
    const float4 v0 = *(const float4*)(embed + src);
    const float4 v1 = *(const float4*)(embed + src + 4);
    const float4 v2 = *(const float4*)(embed + src + 8);
    const float4 v3 = *(const float4*)(embed + src + 12);
    bfrag8 o0 = { f2bf(v0.x), f2bf(v0.y), f2bf(v0.z), f2bf(v0.w),
                  f2bf(v1.x), f2bf(v1.y), f2bf(v1.z), f2bf(v1.w) };
    bfrag8 o1 = { f2bf(v2.x), f2bf(v2.y), f2bf(v2.z), f2bf(v2.w),
                  f2bf(v3.x), f2bf(v3.y), f2bf(v3.z), f2bf(v3.w) };
    *(bfrag8*)(Eg + (long)row * Hz + c0) = o0;
    *(bfrag8*)(Eg + (long)row * Hz + c0 + 8) = o1;
  }
}

// ---------------------------------------------------------------------------
// MFMA GEMM1: y1bf[4096,512] = bf16(relu(Eg @ Wt1^T + b1)).
// K-chunk 64: 2 barriers per 8 MFMA/wave (was per 4).
// ---------------------------------------------------------------------------
__global__ __launch_bounds__(256) void k_mfma1(
    const short* __restrict__ Eg, const short* __restrict__ Wt1,
    const float* __restrict__ b1, short* __restrict__ y1bf)
{
  __shared__ short As[64][64];
  __shared__ short Bs[64][64];
  const int tid = threadIdx.x;
  const int n0 = blockIdx.x * 64, m0 = blockIdx.y * 64;
  const int w = tid >> 6, l = tid & 63;
  const int srow = tid >> 2, skq = (tid & 3) << 3;
  const f32x4v zero = {0.f, 0.f, 0.f, 0.f};
  f32x4v acc[4] = {zero, zero, zero, zero};
  for (int kc = 0; kc < Hz; kc += 64) {
    const bfrag8 a0 = *(const bfrag8*)(Eg + (long)(m0 + srow) * Hz + kc + skq);
    const bfrag8 a1 = *(const bfrag8*)(Eg + (long)(m0 + srow) * Hz + kc + 32 + skq);
    const bfrag8 b0 = *(const bfrag8*)(Wt1 + (long)(n0 + srow) * Hz + kc + skq);
    const bfrag8 b1v = *(const bfrag8*)(Wt1 + (long)(n0 + srow) * Hz + kc + 32 + skq);
    __syncthreads();
    *(bfrag8*)&As[srow][skq]      = a0;
    *(bfrag8*)&As[srow][32 + skq] = a1;
    *(bfrag8*)&Bs[srow][skq]      = b0;
    *(bfrag8*)&Bs[srow][32 + skq] = b1v;
    __syncthreads();
#pragma unroll
    for (int s = 0; s < 2; ++s) {
      const bfrag8 a = *(const bfrag8*)&As[(w << 4) + (l & 15)][(s << 5) + ((l >> 4) << 3)];
#pragma unroll
      for (int nn = 0; nn < 4; ++nn) {
        const bfrag8 bb = *(const bfrag8*)&Bs[(nn << 4) + (l & 15)][(s << 5) + ((l >> 4) << 3)];
        acc[nn] = __builtin_amdgcn_mfma_f32_16x16x32_bf16(a, bb, acc[nn], 0, 0, 0);
      }
    }
  }
  const int col0 = l & 15, quad = l >> 4;
#pragma unroll
  for (int nn = 0; nn < 4; ++nn) {
    const int col = n0 + (nn << 4) + col0;
    const float bias = b1[col];
#pragma unroll
    for (int i = 0; i < 4; ++i) {
      const int row = m0 + (w << 4) + (quad << 2) + i;
      y1bf[(long)row * H2z + col] = f2bf(fmaxf(acc[nn][i] + bias, 0.0f));
    }
  }
}

// ---------------------------------------------------------------------------
// FUSED GEMM2 + residual + LayerNorm + L2-normalize, full-occupancy version.
// Grid: 256 blocks x 16 rows. K-chunk 64 (8 steps, 16 barriers vs 32).
// ---------------------------------------------------------------------------
__global__ __launch_bounds__(256) void k_mfma2ln(
    const int* __restrict__ seq, const float* __restrict__ embed,
    const short* __restrict__ y1bf, const short* __restrict__ Wt2,
    const float* __restrict__ b2, const float* __restrict__ gamma,
    const float* __restrict__ beta, float* __restrict__ h,
    float* __restrict__ hn, short* __restrict__ Knb)
{
  __shared__ short As[16][64];     // 2 KB
  __shared__ short Bs[256][64];    // 32 KB (all 256 output cols of Wt2)
  __shared__ float red[4][16][2];  // per-wave LN partials (s, ss)
  __shared__ float red2[4][16];    // per-wave L2 partials
  const int tid = threadIdx.x;
  const int m0 = blockIdx.x * 16;
  const int w = tid >> 6, l = tid & 63;
  const int srow = tid >> 2, skq = (tid & 3) << 3;
  const f32x4v zero = {0.f, 0.f, 0.f, 0.f};
  f32x4v acc[4] = {zero, zero, zero, zero};

  for (int kc = 0; kc < H2z; kc += 64) {
    bfrag8 av0 = {}, av1 = {};
    if (tid < 64) {
      av0 = *(const bfrag8*)(y1bf + (long)(m0 + (tid >> 2)) * H2z + kc + skq);
      av1 = *(const bfrag8*)(y1bf + (long)(m0 + (tid >> 2)) * H2z + kc + 32 + skq);
    }
    bfrag8 bv0[4], bv1[4];
#pragma unroll
    for (int q = 0; q < 4; ++q) {
      bv0[q] = *(const bfrag8*)(Wt2 + (long)(srow + (q << 6)) * H2z + kc + skq);
      bv1[q] = *(const bfrag8*)(Wt2 + (long)(srow + (q << 6)) * H2z + kc + 32 + skq);
    }
    __syncthreads();
    if (tid < 64) {
      *(bfrag8*)&As[tid >> 2][skq]      = av0;
      *(bfrag8*)&As[tid >> 2][32 + skq] = av1;
    }
#pragma unroll
    for (int q = 0; q < 4; ++q) {
      *(bfrag8*)&Bs[srow + (q << 6)][skq]      = bv0[q];
      *(bfrag8*)&Bs[srow + (q << 6)][32 + skq] = bv1[q];
    }
    __syncthreads();
#pragma unroll
    for (int s = 0; s < 2; ++s) {
      const bfrag8 a = *(const bfrag8*)&As[l & 15][(s << 5) + ((l >> 4) << 3)];
#pragma unroll
      for (int nn = 0; nn < 4; ++nn) {
        const bfrag8 bb =
            *(const bfrag8*)&Bs[(w << 6) + (nn << 4) + (l & 15)][(s << 5) + ((l >> 4) << 3)];
        acc[nn] = __builtin_amdgcn_mfma_f32_16x16x32_bf16(a, bb, acc[nn], 0, 0, 0);
      }
    }
  }

  const int col0 = l & 15, quad = l >> 4;
  float g_r[4], be_r[4], b2_r[4];
#pragma unroll
  for (int nn = 0; nn < 4; ++nn) {
    const int col = (w << 6) + (nn << 4) + col0;
    g_r[nn] = gamma[col]; be_r[nn] = beta[col]; b2_r[nn] = b2[col];
  }

  // pass 1: residual add, per-row mean/var partials (this wave's 64 cols)
  float v[4][4];                    // [i][nn]
#pragma unroll
  for (int i = 0; i < 4; ++i) {
    const int lr = (quad << 2) + i;
    const int row = m0 + lr;
    const long ebase = (long)seq[row] * Hz;
    float s = 0.0f, ss = 0.0f;
#pragma unroll
    for (int nn = 0; nn < 4; ++nn) {
      const int col = (w << 6) + (nn << 4) + col0;
      const float t = acc[nn][i] + b2_r[nn] + embed[ebase + col];
      v[i][nn] = t; s += t; ss += t * t;
    }
#pragma unroll
    for (int o = 8; o >= 1; o >>= 1) { s += __shfl_xor(s, o); ss += __shfl_xor(ss, o); }
    if ((l & 15) == 0) { red[w][lr][0] = s; red[w][lr][1] = ss; }
  }
  __syncthreads();

  // pass 2: LN normalize, per-row L2 partials
#pragma unroll
  for (int i = 0; i < 4; ++i) {
    const int lr = (quad << 2) + i;
    const float s  = red[0][lr][0] + red[1][lr][0] + red[2][lr][0] + red[3][lr][0];
    const float ss = red[0][lr][1] + red[1][lr][1] + red[2][lr][1] + red[3][lr][1];
    const float mu   = s * (1.0f / Hz);
    const float var  = ss * (1.0f / Hz) - mu * mu;
    const float rstd = rsqrtf(var + 1e-5f);
    float hs = 0.0f;
#pragma unroll
    for (int nn = 0; nn < 4; ++nn) {
      const float hv = (v[i][nn] - mu) * rstd * g_r[nn] + be_r[nn];
      v[i][nn] = hv; hs += hv * hv;
    }
#pragma unroll
    for (int o = 8; o >= 1; o >>= 1) hs += __shfl_xor(hs, o);
    if ((l & 15) == 0) red2[w][lr] = hs;
  }
  __syncthreads();

  // pass 3: L2 normalize + stores
#pragma unroll
  for (int i = 0; i < 4; ++i) {
    const int lr = (quad << 2) + i;
    const float hs = red2[0][lr] + red2[1][lr] + red2[2][lr] + red2[3][lr];
    const float inv = 1.0f / fmaxf(sqrtf(hs), 1e-12f);
    const int row = m0 + lr;
    float* hrow  = h  + (long)row * Hz;
    float* hnrow = hn + (long)row * Hz;
    const int bb_ = row >> 9, t = row & 511;
    short* kr = Knb + ((long)bb_ * 512 + (t < 511 ? 510 - t : 511)) * Hz;
#pragma unroll
    for (int nn = 0; nn < 4; ++nn) {
      const int col = (w << 6) + (nn << 4) + col0;
      const float hv = v[i][nn];
      const float nv = hv * inv;
      hrow[col]  = hv;
      hnrow[col] = nv;
      kr[col] = (t < 511) ? f2bf(nv) : (short)0;
    }
  }
}

// ---------------------------------------------------------------------------
// Full Gram via bf16 MFMA (lower tiles), K-chunk 64; diagonal tiles reuse As
// as B operand (skip Bs staging). FUSED block-diag inverse + fused p on idle
// upper blocks.
// ---------------------------------------------------------------------------
__global__ __launch_bounds__(256) void k_gramT(
    const short* __restrict__ Knb, const float* __restrict__ h,
    const float* __restrict__ hn, float* __restrict__ G,
    float* __restrict__ Wsol, float* __restrict__ p)
{
  const int nb = blockIdx.x, mb = blockIdx.y, b = blockIdx.z;
  __shared__ short As[64][64];
  __shared__ short Bs[64][64];
  __shared__ float Gs2[2][32][33];
  __shared__ float qs[Hz];
  if (nb > mb) {
    // repurposed idle block: p chunk (block-uniform branch, syncthreads legal)
    const int idx = ((nb * (nb - 1)) >> 1) + mb;   // 0..27 upper-tri enumeration
    if (idx >= 16) return;
    const int tid = threadIdx.x;
    qs[tid] = h[((long)b * Lz + 511) * Hz + tid];
    __syncthreads();
    const int s = idx * 32 + (tid >> 3);           // 32 s-rows per block
    const int g = tid & 7;                         // 8 threads per row, 32 ch each
    float acc = 0.0f;
    if (s <= 510) {
      const float* src = hn + ((long)b * Lz + (510 - s)) * Hz + (g << 5);
#pragma unroll
      for (int q = 0; q < 8; ++q) {
        const float4 vv = *(const float4*)(src + 4 * q);
        const int c = (g << 5) + 4 * q;
        acc += vv.x * qs[c] + vv.y * qs[c + 1] + vv.z * qs[c + 2] + vv.w * qs[c + 3];
      }
    }
#pragma unroll
    for (int o = 4; o >= 1; o >>= 1) acc += __shfl_xor(acc, o);
    if (g == 0) p[(long)b * 512 + s] = acc;        // s==511 writes 0 (dummy)
    return;
  }
  const short* Kb = Knb + (long)b * 512 * Hz;
  const int tid = threadIdx.x;
  const int w = tid >> 6, l = tid & 63;
  const int srow = tid >> 2, skq = (tid & 3) << 3;
  const bool diag = (mb == nb);
  const f32x4v zero = {0.f, 0.f, 0.f, 0.f};
  f32x4v acc[4] = {zero, zero, zero, zero};
  for (int kc = 0; kc < Hz; kc += 64) {
    const bfrag8 a0 = *(const bfrag8*)(Kb + (long)(mb * 64 + srow) * Hz + kc + skq);
    const bfrag8 a1 = *(const bfrag8*)(Kb + (long)(mb * 64 + srow) * Hz + kc + 32 + skq);
    bfrag8 b0, b1;
    if (!diag) {
      b0 = *(const bfrag8*)(Kb + (long)(nb * 64 + srow) * Hz + kc + skq);
      b1 = *(const bfrag8*)(Kb + (long)(nb * 64 + srow) * Hz + kc + 32 + skq);
    }
    __syncthreads();
    *(bfrag8*)&As[srow][skq]      = a0;
    *(bfrag8*)&As[srow][32 + skq] = a1;
    if (!diag) {
      *(bfrag8*)&Bs[srow][skq]      = b0;
      *(bfrag8*)&Bs[srow][32 + skq] = b1;
    }
    __syncthreads();
#pragma unroll
    for (int s = 0; s < 2; ++s) {
      const bfrag8 a = *(const bfrag8*)&As[(w << 4) + (l & 15)][(s << 5) + ((l >> 4) << 3)];
#pragma unroll
      for (int nn = 0; nn < 4; ++nn) {
        const bfrag8 bb = diag
            ? *(const bfrag8*)&As[(nn << 4) + (l & 15)][(s << 5) + ((l >> 4) << 3)]
            : *(const bfrag8*)&Bs[(nn << 4) + (l & 15)][(s << 5) + ((l >> 4) << 3)];
        acc[nn] = __builtin_amdgcn_mfma_f32_16x16x32_bf16(a, bb, acc[nn], 0, 0, 0);
      }
    }
  }
  const int col0 = l & 15, quad = l >> 4;
  float* Gb = G + (long)b * 512 * 512;
#pragma unroll
  for (int nn = 0; nn < 4; ++nn) {
    const int col = nb * 64 + (nn << 4) + col0;
#pragma unroll
    for (int i = 0; i < 4; ++i) {
      const int row = mb * 64 + (w << 4) + (quad << 2) + i;
      Gb[(long)row * 512 + col] = acc[nn][i];
    }
  }
  if (!diag) return;
#pragma unroll
  for (int nn = 0; nn < 4; ++nn) {
    const int lc = (nn << 4) + col0;
#pragma unroll
    for (int i = 0; i < 4; ++i) {
      const int lr = (w << 4) + (quad << 2) + i;
      if ((lr >> 5) == (lc >> 5)) Gs2[lr >> 5][lr & 31][lc & 31] = acc[nn][i];
    }
  }
  __syncthreads();
  if (w < 2 && l < 32) {       // wave w inverts sub-block w; lane = column c
    const int c = l;
    float wv[32];
    wv[0] = (c == 0) ? 1.0f : 0.0f;
#pragma unroll
    for (int i = 1; i < 32; ++i) {
      float sum = 0.0f;
#pragma unroll
      for (int j = 0; j < i; ++j) sum = fmaf(Gs2[w][i][j], wv[j], sum);
      wv[i] = ((i == c) ? 1.0f : 0.0f) - CF * sum;
    }
    const int blk = mb * 2 + w;
    float* dst = Wsol + ((long)(b * NB + blk) << 10) + c;
#pragma unroll
    for (int i = 0; i < 32; ++i) dst[i * 32] = wv[i];
  }
}

// ---------------------------------------------------------------------------
// Block-triangular solve with REGISTER PREFETCH + split diag matvec:
// wave0's 64 lanes pair up (row = tid&31, half = tid>>5) so the 32-deep
// dependent Wsol.rhs fma chain becomes 16-deep + one __shfl_xor combine.
// ---------------------------------------------------------------------------
__global__ __launch_bounds__(256) void k_solve(
    const float* __restrict__ G, const float* __restrict__ p,
    const float* __restrict__ Wsol, float* __restrict__ d_all)
{
  __shared__ float ds[512];
  __shared__ float part[32][9];
  __shared__ float rhs[32];
  const int b = blockIdx.x, tid = threadIdx.x;
  const int i = tid >> 3, g = tid & 7;
  const float* Gb = G + (long)b * 512 * 512;
  const float* pb = p + (long)b * 512;

  float4 gbuf[15];                 // G[blk*32+i][bp*32+g*4] for current step
  float4 wbuf[4];                  // wave0: half a Wsol row (16 elems)
  float  pcur = 0.0f;
  const int row = tid & 31, half = (tid >> 5) & 1;
  if (tid < 64) {
#pragma unroll
    for (int k = 0; k < 4; ++k)
      wbuf[k] = *(const float4*)(Wsol + ((long)(b * NB) << 10) +
                                 row * 32 + half * 16 + (k << 2));
    if (tid < 32) pcur = pb[tid];
  }

  for (int blk = 0; blk < NB; ++blk) {
    // off-diagonal matvec using prefetched gbuf (empty at blk=0)
    float acc = 0.0f;
#pragma unroll
    for (int bp = 0; bp < 15; ++bp) {
      if (bp < blk) {
        const int j = bp * 32 + (g << 2);
        acc += gbuf[bp].x * ds[j]     + gbuf[bp].y * ds[j + 1] +
               gbuf[bp].z * ds[j + 2] + gbuf[bp].w * ds[j + 3];
      }
    }
    part[i][g] = acc;
    // issue G prefetch for step blk+1 (independent of ds; hides under barriers)
    if (blk + 1 < NB) {
      const float* grow = Gb + (long)((blk + 1) * 32 + i) * 512 + (g << 2);
#pragma unroll
      for (int bp = 0; bp < 15; ++bp)
        if (bp <= blk) gbuf[bp] = *(const float4*)(grow + bp * 32);
    }
    __syncthreads();
    if (tid < 64) {               // wave 0 only, wave-synchronous from here
      if (tid < 32) {
        const float c = part[tid][0] + part[tid][1] + part[tid][2] + part[tid][3] +
                        part[tid][4] + part[tid][5] + part[tid][6] + part[tid][7];
        rhs[tid] = pcur - CF * c;
      }
      // rhs written by lanes 0-31, read by all 64 lanes of this wave (lockstep)
      float dvh = 0.0f;
#pragma unroll
      for (int k = 0; k < 4; ++k) {
        const int k0 = half * 16 + (k << 2);
        dvh += wbuf[k].x * rhs[k0]     + wbuf[k].y * rhs[k0 + 1] +
               wbuf[k].z * rhs[k0 + 2] + wbuf[k].w * rhs[k0 + 3];
      }
      float dv = dvh + __shfl_xor(dvh, 32);
      if (tid < 32) {
        if (blk == NB - 1 && tid == 31) dv = 0.0f;   // dummy s=511
        ds[blk * 32 + tid] = dv;
        d_all[(long)b * 512 + blk * 32 + tid] = dv;
        if (blk + 1 < NB) pcur = pb[(blk + 1) * 32 + tid];
      }
      // prefetch Wsol for step blk+1
      if (blk + 1 < NB) {
#pragma unroll
        for (int k = 0; k < 4; ++k)
          wbuf[k] = *(const float4*)(Wsol + ((long)(b * NB + blk + 1) << 10) +
                                     row * 32 + half * 16 + (k << 2));
      }
    }
    __syncthreads();
  }
}

// ---------------------------------------------------------------------------
// m partials, float4-vectorized: chunk c covers 16 t; wave w handles
// t = t0 + {w, w+4, w+8, w+12}; lane loads dwordx4 of the h row.
// 256 blocks — full-occupancy version (grid-8 fusion was latency-bound: 46 us).
// ---------------------------------------------------------------------------
__global__ __launch_bounds__(256) void k_mrp(
    const float* __restrict__ h, const float* __restrict__ d_all,
    float* __restrict__ part)
{
  __shared__ float acc_s[4][Hz];
  const int c = blockIdx.x, b = blockIdx.y, tid = threadIdx.x;
  const int w = tid >> 6, lane = tid & 63;
  const float* hb = h + (long)b * Lz * Hz;
  const float* db = d_all + ((long)b << 9);
  const int t0 = c * 16;
  const int off = lane << 2;
  float4 acc = {0.f, 0.f, 0.f, 0.f};
#pragma unroll
  for (int q = 0; q < 4; ++q) {
    const int t = t0 + (q << 2) + w;
    if (t < 511) {
      const float dv = db[510 - t];
      const float4 hv = *(const float4*)(hb + (long)t * Hz + off);
      acc.x = fmaf(dv, hv.x, acc.x); acc.y = fmaf(dv, hv.y, acc.y);
      acc.z = fmaf(dv, hv.z, acc.z); acc.w = fmaf(dv, hv.w, acc.w);
    }
  }
  *(float4*)&acc_s[w][off] = acc;
  __syncthreads();
  if (tid < Hz) {
    part[((long)b * 32 + c) * Hz + tid] =
        acc_s[0][tid] + acc_s[1][tid] + acc_s[2][tid] + acc_s[3][tid];
  }
}

// ---------------------------------------------------------------------------
// Combine partials -> m; r = m @ Wrp + brp.  Parallel version: grid (4, Bz),
// 64 cols per block, 4 e-groups of 64 per thread-col, coalesced Wrp reads,
// 4-way LDS reduce. (8-WG version was latency-bound: strided serial loads.)
// ---------------------------------------------------------------------------
__global__ __launch_bounds__(256) void k_mr2(
    const float* __restrict__ part, const float* __restrict__ Wrp,
    const float* __restrict__ brp, float* __restrict__ r)
{
  __shared__ float ms[Hz];
  __shared__ float red[4][64];
  const int c4 = blockIdx.x, b = blockIdx.y, tid = threadIdx.x;
  const int lane = tid & 63, eg = tid >> 6;
  float a = 0.0f;
#pragma unroll
  for (int c = 0; c < 32; ++c) a += part[((long)b * 32 + c) * Hz + tid];
  ms[tid] = CF * a;
  __syncthreads();
  const int col = (c4 << 6) + lane;
  float racc = 0.0f;
#pragma unroll 16
  for (int k = 0; k < 64; ++k) {
    const int e = (eg << 6) + k;
    racc = fmaf(ms[e], Wrp[(long)e * Hz + col], racc);
  }
  red[eg][lane] = racc;
  __syncthreads();
  if (tid < 64)
    r[b * Hz + (c4 << 6) + tid] =
        red[0][tid] + red[1][tid] + red[2][tid] + red[3][tid] + brp[(c4 << 6) + tid];
}

// ---------------------------------------------------------------------------
// out[8,32000] = r[8,256] @ Wout[256,32000] + bout.
// ---------------------------------------------------------------------------
__global__ __launch_bounds__(256) void k_outproj(
    const float* __restrict__ r, const float* __restrict__ Wout,
    const float* __restrict__ bout, float* __restrict__ out)
{
  __shared__ float rs[8 * Hz];
  __shared__ float part[4][8][64];
  const int tid = threadIdx.x, w = tid >> 6, lane = tid & 63;
  ((float4*)rs)[tid * 2 + 0] = ((const float4*)r)[tid * 2 + 0];
  ((float4*)rs)[tid * 2 + 1] = ((const float4*)r)[tid * 2 + 1];
  __syncthreads();
  const int col = blockIdx.x * 64 + lane;
  float acc[8] = {};
  const int i0 = w << 6;
#pragma unroll 8
  for (int ii = 0; ii < 64; ++ii) {
    const int i = i0 + ii;
    const float wv = Wout[(long)i * Vz + col];
#pragma unroll
    for (int bb = 0; bb < 8; ++bb) acc[bb] = fmaf(rs[bb * Hz + i], wv, acc[bb]);
  }
#pragma unroll
  for (int bb = 0; bb < 8; ++bb) part[w][bb][lane] = acc[bb];
  __syncthreads();
  const float bo = bout[col];
  float s0 = part[0][w][lane] + part[1][w][lane] + part[2][w][lane] + part[3][w][lane];
  out[(long)w * Vz + col] = s0 + bo;
  const int w4 = w + 4;
  float s1 = part[0][w4][lane] + part[1][w4][lane] + part[2][w4][lane] + part[3][w4][lane];
  out[(long)w4 * Vz + col] = s1 + bo;
}

// ---------------------------------------------------------------------------
extern "C" void kernel_launch(void* const* d_in, const int* in_sizes, int n_in,
                              void* d_out, int out_size, void* d_ws, size_t ws_size,
                              hipStream_t stream)
{
  const int*   seq   = (const int*)  d_in[0];
  const float* embed = (const float*)d_in[1];
  const float* W1    = (const float*)d_in[2];
  const float* b1    = (const float*)d_in[3];
  const float* W2    = (const float*)d_in[4];
  const float* b2    = (const float*)d_in[5];
  const float* gamma = (const float*)d_in[6];
  const float* beta  = (const float*)d_in[7];
  const float* Wrp   = (const float*)d_in[8];
  const float* brp   = (const float*)d_in[9];
  const float* Wout  = (const float*)d_in[10];
  const float* bout  = (const float*)d_in[11];
  float* out = (float*)d_out;

  char* ws = (char*)d_ws;
  const size_t MB = 1024u * 1024u;
  // Temporal overlay: y1bf dies after k_mfma2ln; Gf written by k_gramT (later).
  short* y1bf = (short*)(ws);                        // 4 MB  [0,4)
  float* Gf   = (float*)(ws);                        // 8 MB  [0,8)  (after mfma2ln)
  float* hb   = (float*)(ws + 8 * MB);               // 4 MB
  float* hnb  = (float*)(ws + 12 * MB);              // 4 MB
  short* Knb  = (short*)(ws + 16 * MB);              // 2 MB  bf16 s-order keys
  short* Wt1  = (short*)(ws + 18 * MB);              // 256 KB
  short* Wt2  = (short*)(ws + 18 * MB + 256 * 1024); // 256 KB
  float* Wsol = (float*)(ws + 18 * MB + 512 * 1024); // 512 KB
  float* pbuf = (float*)(ws + 19 * MB);                        // 16 KB
  float* dall = (float*)(ws + 19 * MB + 16 * 1024);            // 16 KB
  float* prt  = (float*)(ws + 19 * MB + 32 * 1024);            // 256 KB
  float* rb   = (float*)(ws + 19 * MB + 288 * 1024);           // 8 KB
  short* Eg   = (short*)(ws + 20 * MB);              // 2 MB bf16 gathered embed

  k_wcvt2<<<320, 256, 0, stream>>>(W1, W2, seq, embed, Wt1, Wt2, Eg);
  k_mfma1<<<dim3(H2z / 64, Mz / 64), 256, 0, stream>>>(Eg, Wt1, b1, y1bf);
  k_mfma2ln<<<Mz / 16, 256, 0, stream>>>(seq, embed, y1bf, Wt2, b2, gamma, beta,
                                         hb, hnb, Knb);
  k_gramT<<<dim3(8, 8, Bz), 256, 0, stream>>>(Knb, hb, hnb, Gf, Wsol, pbuf);
  k_solve<<<Bz, 256, 0, stream>>>(Gf, pbuf, Wsol, dall);
  k_mrp<<<dim3(32, Bz), 256, 0, stream>>>(hb, dall, prt);
  k_mr2<<<dim3(4, Bz), 256, 0, stream>>>(prt, Wrp, brp, rb);
  k_outproj<<<Vz / 64, 256, 0, stream>>>(rb, Wout, bout, out);
}